// Round 5
// baseline (2933.304 us; speedup 1.0000x reference)
//
#include <hip/hip_runtime.h>
#include <cmath>

#define TPB 256

// ---- problem constants (fixed by setup_inputs) ----
constexpr int Bb = 32, Cc = 256, Ff = 1024, Oo = 201;
constexpr int H0 = 10, S0 = 8,  N0 = Bb * S0 * S0;   // 2048
constexpr int H1 = 20, S1 = 18, N1 = Bb * S1 * S1;   // 10368
constexpr int NT_ALL = N0 + N1;                      // 12416
constexpr int KC = Cc * 9;                           // 2304 (natural K)
constexpr int KP = Cc * 16;                          // 4096 (tap-padded K: k' = c*16 + t, taps 9..15 zero)
constexpr int L5 = S0 * S0;                          // 64
constexpr int L4 = S1 * S1;                          // 324
constexpr int LT = L5 + L4;                          // 388

// ---- element counts ----
constexpr size_t SZ_CWP = (size_t)Ff * KP;      // 4,194,304 (padded)
constexpr size_t SZ_W0P = (size_t)Cc * KP;      // 1,048,576 (padded)
constexpr size_t SZ_LW  = (size_t)Oo * Ff;      // 205,824
constexpr size_t NFEAT  = (size_t)NT_ALL * Ff;  // 12,713,984

// ---- workspace byte offsets (time-disjoint aliasing) ----
constexpr size_t B_CWH   = 0;
constexpr size_t B_CWL   = B_CWH + SZ_CWP * 2;           //  8,388,608
constexpr size_t B_W0H   = B_CWL + SZ_CWP * 2;           // 16,777,216
constexpr size_t B_W0L   = B_W0H + SZ_W0P * 2;           // 18,874,368
constexpr size_t B_GXY   = B_W0L + SZ_W0P * 2;           // 20,971,520
constexpr size_t B_LWH   = B_GXY + (size_t)NT_ALL * 18 * 4; // 21,865,472
constexpr size_t B_LWL   = B_LWH + SZ_LW * 2;            // 22,277,120
constexpr size_t B_FEATH = B_LWL + SZ_LW * 2;            // 22,688,768
constexpr size_t B_FEATL = B_FEATH + NFEAT * 2;          // 48,116,736
constexpr size_t B_MX    = B_FEATL + NFEAT * 2;          // 73,544,704
constexpr size_t B_SM    = B_MX + 128;
constexpr size_t B_RP    = B_SM + 128;
constexpr size_t B_END   = B_RP + 128;                   // ~73.5 MB (known ws >= 78.4 MB)
// aliases (disjoint lifetimes):
constexpr size_t B_SC = B_CWH;    // sc (9.98 MB) over cw splits (dead when scores run)
constexpr size_t B_C2 = B_W0H;    // c2 (0.30 MB) over w0 splits (dead after conv1)
constexpr size_t B_H0 = B_FEATH;  // h (16.4 MB) over feat (written later)
constexpr size_t B_H1 = B_H0 + (size_t)Bb * Cc * H0 * H0 * 4;

// ---- output layout (floats) ----
constexpr size_t O_LIK = 0;
constexpr size_t O_BOX = O_LIK + Bb * Oo;
constexpr size_t O_NT  = O_BOX + Bb * 5;
constexpr size_t O_TD  = O_NT + Bb * 5;
constexpr size_t O_REG = O_TD + (size_t)NT_ALL * 6;

typedef __attribute__((ext_vector_type(8))) short bf16x8;
typedef __attribute__((ext_vector_type(4))) float f32x4;

__device__ __forceinline__ short f2bf(float f) {
    unsigned u = __builtin_bit_cast(unsigned, f);
    u += 0x7fffu + ((u >> 16) & 1u);
    return (short)(u >> 16);
}
__device__ __forceinline__ float bf2f(short s) {
    unsigned u = ((unsigned)(unsigned short)s) << 16;
    return __builtin_bit_cast(float, u);
}
__device__ __forceinline__ float clampf(float x, float lo, float hi) {
    return fminf(fmaxf(x, lo), hi);
}

// =====================================================================
// weight split kernels: fp32 -> (hi, lo) bf16.
// splitp16: src k = c*9 + t  ->  dst k' = c*16 + t,  taps 9..15 = 0
// =====================================================================
__global__ __launch_bounds__(TPB)
void splitp16_k(const float* __restrict__ src, short* __restrict__ hi,
                short* __restrict__ lo, int nrows)
{
    int idx = blockIdx.x * TPB + threadIdx.x;
    if (idx >= nrows * KP) return;
    int row = idx >> 12, kq = idx & (KP - 1);
    int c = kq >> 4, t = kq & 15;
    float v = (t < 9) ? src[(size_t)row * KC + c * 9 + t] : 0.f;
    short hs = f2bf(v);
    hi[idx] = hs;
    lo[idx] = f2bf(v - bf2f(hs));
}

__global__ __launch_bounds__(TPB)
void split_k(const float* __restrict__ src, short* __restrict__ hi,
             short* __restrict__ lo, int n)
{
    int idx = blockIdx.x * TPB + threadIdx.x;
    if (idx >= n) return;
    float v = src[idx];
    short hs = f2bf(v);
    hi[idx] = hs;
    lo[idx] = f2bf(v - bf2f(hs));
}

// =====================================================================
// Split-bf16 MFMA GEMM: out(MxN) = A(MxK) * Bw(NxK)^T (+bias, act)
// Block 128x128, BK=32, 4 waves, mfma_f32_16x16x32_bf16, 3 MFMAs/pair.
// MODE 0/2: K tap-padded (KD=KP, k=c*16+t). Per K-step channels
//   {c0,c0+1} staged into an LDS slab with ROW STRIDE H+1 (odd ->
//   conflict-free lane-stride gathers); A gathered from slab via
//   per-row tap tables (compile-time tap indices -> registers).
// MODE 0: A = im2col pad=1 of Asrc (NCHW HxH); epilogue relu fp32 -> h
// MODE 2: A = bilinear sample of Asrc at gxy; epilogue feat hi/lo bf16
// MODE 3: A = pre-split rows (KD=1024, natural); epilogue score scatter
// GRID: dim3(nN, nM) -- n fastest; nN | 8 pins each XCD to one B-strip.
// =====================================================================
template<int MODE, int H, int S, int M, int N, int KD, int POS>
__global__ __launch_bounds__(TPB, 4)
void mgemm(const float* __restrict__ Asrc,
           const short* __restrict__ AsrcH, const short* __restrict__ AsrcL,
           const float* __restrict__ gxy,
           const short* __restrict__ Bh, const short* __restrict__ Bl,
           const float* __restrict__ bias,
           float* __restrict__ outF, short* __restrict__ outH, short* __restrict__ outL)
{
    constexpr int HP   = H + 1;                       // padded row stride (odd)
    constexpr int PLSZ = H * H;                       // natural plane floats
    constexpr int PLP  = H * HP;                      // padded plane floats
    constexpr int RPI  = (MODE == 0) ? H * H : S * S; // rows per image
    constexpr int NBI  = (MODE == 3) ? 1 : (127 / RPI + 2); // max images/tile

    __shared__ short As[2][4][128][8];   // 16KB
    __shared__ short Bs[2][4][128][8];   // 16KB
    __shared__ float slab[(MODE == 3) ? 1 : NBI * 2 * PLP];

    const int tid = threadIdx.x;
    const int lane = tid & 63;
    const int wid = tid >> 6;
    const int wm = (wid >> 1) * 64, wn = (wid & 1) * 64;
    const int ml = tid & 127, kg0 = tid >> 7;
    const int bm = blockIdx.y * 128, bn = blockIdx.x * 128;   // n fastest

    f32x4 acc[4][4];
    #pragma unroll
    for (int i = 0; i < 4; i++)
        #pragma unroll
        for (int j = 0; j < 4; j++)
            acc[i][j] = (f32x4){0.f, 0.f, 0.f, 0.f};

    const int mG = bm + ml;
    const int nG = bn + ml;

    // ---- per-row tap tables (compile-time indexed => registers) ----
    int bat0 = 0, batidx = 0, nb = 1;
    float w00t[9], w01t[9], w10t[9], w11t[9];
    int o00t[9], o01t[9], o10t[9], o11t[9];
    float wvt[9];
    int offt[9];

    if constexpr (MODE == 0) {
        bat0 = bm / RPI;
        nb = (bm + 127) / RPI - bat0 + 1;
        int bA = mG / RPI; int rem = mG - bA * RPI;
        int yA = rem / H, xA = rem - (rem / H) * H;
        batidx = bA - bat0;
        #pragma unroll
        for (int t = 0; t < 9; t++) {
            int ky = t / 3 - 1, kx = t - (t / 3) * 3 - 1;
            int yy = yA + ky, xx = xA + kx;
            bool ok = (yy >= 0 && yy < H && xx >= 0 && xx < H);
            offt[t] = ok ? (yy * HP + xx) : 0;
            wvt[t] = ok ? 1.f : 0.f;
        }
    } else if constexpr (MODE == 2) {
        bat0 = bm / RPI;
        nb = (bm + 127) / RPI - bat0 + 1;
        int bA = mG / RPI;
        batidx = bA - bat0;
        #pragma unroll
        for (int t = 0; t < 9; t++) {
            float gx = gxy[(size_t)mG * 18 + t];
            float gy = gxy[(size_t)mG * 18 + 9 + t];
            float xf = floorf(gx), yf = floorf(gy);
            float wx = gx - xf, wy = gy - yf;
            int ix = (int)xf, iy = (int)yf;
            int cx0 = min(max(ix, 0), H - 1), cx1 = min(max(ix + 1, 0), H - 1);
            int cy0 = min(max(iy, 0), H - 1), cy1 = min(max(iy + 1, 0), H - 1);
            float vx0 = (ix >= 0 && ix < H) ? 1.f : 0.f;
            float vx1 = (ix + 1 >= 0 && ix + 1 < H) ? 1.f : 0.f;
            float vy0 = (iy >= 0 && iy < H) ? 1.f : 0.f;
            float vy1 = (iy + 1 >= 0 && iy + 1 < H) ? 1.f : 0.f;
            w00t[t] = (1.f - wy) * (1.f - wx) * vy0 * vx0;
            w01t[t] = (1.f - wy) * wx * vy0 * vx1;
            w10t[t] = wy * (1.f - wx) * vy1 * vx0;
            w11t[t] = wy * wx * vy1 * vx1;
            o00t[t] = cy0 * HP + cx0; o01t[t] = cy0 * HP + cx1;
            o10t[t] = cy1 * HP + cx0; o11t[t] = cy1 * HP + cx1;
        }
    }

    for (int kb = 0; kb < KD; kb += 32) {
        // ---------- phase 0: slab stage (channels c0, c0+1), row-padded ----------
        if constexpr (MODE == 0 || MODE == 2) {
            const int c0 = kb >> 4;
            constexpr int UPP = PLSZ / 4;            // float4 units per plane
            const int nu = nb * 2 * UPP;
            for (int i = tid; i < nu; i += TPB) {
                int pl = i / UPP, u = i - pl * UPP;
                int bi = pl >> 1, cc = pl & 1;
                float4 v = *(const float4*)(Asrc + ((size_t)(bat0 + bi) * Cc + c0 + cc) * PLSZ + u * 4);
                #pragma unroll
                for (int e = 0; e < 4; e++) {
                    int p = u * 4 + e;
                    int row = p / H, col = p - row * H;
                    slab[pl * PLP + row * HP + col] = ((const float*)&v)[e];
                }
            }
            __syncthreads();
        }
        // ---------- phase 1: A-stage from slab; B-stage ----------
        if constexpr (MODE == 0) {
            const float* sp = &slab[(batidx * 2 + kg0) * PLP];
            bf16x8 hv, lv;
            #pragma unroll
            for (int e = 0; e < 8; e++) {
                float v = sp[offt[e]] * wvt[e];
                short hs = f2bf(v); hv[e] = hs; lv[e] = f2bf(v - bf2f(hs));
            }
            *(bf16x8*)&As[0][kg0 * 2][ml][0] = hv;
            *(bf16x8*)&As[1][kg0 * 2][ml][0] = lv;
            bf16x8 hv2 = {}, lv2 = {};
            {
                float v = sp[offt[8]] * wvt[8];
                short hs = f2bf(v); hv2[0] = hs; lv2[0] = f2bf(v - bf2f(hs));
            }
            *(bf16x8*)&As[0][kg0 * 2 + 1][ml][0] = hv2;
            *(bf16x8*)&As[1][kg0 * 2 + 1][ml][0] = lv2;
        } else if constexpr (MODE == 2) {
            const float* sp = &slab[(batidx * 2 + kg0) * PLP];
            bf16x8 hv, lv;
            #pragma unroll
            for (int e = 0; e < 8; e++) {
                float v = sp[o00t[e]] * w00t[e] + sp[o01t[e]] * w01t[e]
                        + sp[o10t[e]] * w10t[e] + sp[o11t[e]] * w11t[e];
                short hs = f2bf(v); hv[e] = hs; lv[e] = f2bf(v - bf2f(hs));
            }
            *(bf16x8*)&As[0][kg0 * 2][ml][0] = hv;
            *(bf16x8*)&As[1][kg0 * 2][ml][0] = lv;
            bf16x8 hv2 = {}, lv2 = {};
            {
                float v = sp[o00t[8]] * w00t[8] + sp[o01t[8]] * w01t[8]
                        + sp[o10t[8]] * w10t[8] + sp[o11t[8]] * w11t[8];
                short hs = f2bf(v); hv2[0] = hs; lv2[0] = f2bf(v - bf2f(hs));
            }
            *(bf16x8*)&As[0][kg0 * 2 + 1][ml][0] = hv2;
            *(bf16x8*)&As[1][kg0 * 2 + 1][ml][0] = lv2;
        } else { // MODE 3
            #pragma unroll
            for (int hh = 0; hh < 2; hh++) {
                int kg = kg0 * 2 + hh;
                *(bf16x8*)&As[0][kg][ml][0] = *(const bf16x8*)(AsrcH + (size_t)mG * KD + kb + kg * 8);
                *(bf16x8*)&As[1][kg][ml][0] = *(const bf16x8*)(AsrcL + (size_t)mG * KD + kb + kg * 8);
            }
        }
        #pragma unroll
        for (int hh = 0; hh < 2; hh++) {
            int kg = kg0 * 2 + hh;
            bf16x8 hv = {}, lv = {};
            if (nG < N) {
                hv = *(const bf16x8*)(Bh + (size_t)nG * KD + kb + kg * 8);
                lv = *(const bf16x8*)(Bl + (size_t)nG * KD + kb + kg * 8);
            }
            *(bf16x8*)&Bs[0][kg][ml][0] = hv;
            *(bf16x8*)&Bs[1][kg][ml][0] = lv;
        }
        __syncthreads();
        // ---------- phase 2: MFMA ----------
        {
            const int kq = lane >> 4, r = lane & 15;
            bf16x8 ah[4], al[4], bhf[4], blf[4];
            #pragma unroll
            for (int i = 0; i < 4; i++) {
                ah[i]  = *(const bf16x8*)&As[0][kq][wm + i * 16 + r][0];
                al[i]  = *(const bf16x8*)&As[1][kq][wm + i * 16 + r][0];
                bhf[i] = *(const bf16x8*)&Bs[0][kq][wn + i * 16 + r][0];
                blf[i] = *(const bf16x8*)&Bs[1][kq][wn + i * 16 + r][0];
            }
            #pragma unroll
            for (int i = 0; i < 4; i++)
                #pragma unroll
                for (int j = 0; j < 4; j++) {
                    acc[i][j] = __builtin_amdgcn_mfma_f32_16x16x32_bf16(ah[i], bhf[j], acc[i][j], 0, 0, 0);
                    acc[i][j] = __builtin_amdgcn_mfma_f32_16x16x32_bf16(al[i], bhf[j], acc[i][j], 0, 0, 0);
                    acc[i][j] = __builtin_amdgcn_mfma_f32_16x16x32_bf16(ah[i], blf[j], acc[i][j], 0, 0, 0);
                }
        }
        __syncthreads();
    }

    // ---------- epilogue ----------
    const int kq = lane >> 4, rr = lane & 15;
    #pragma unroll
    for (int i = 0; i < 4; i++) {
        #pragma unroll
        for (int r = 0; r < 4; r++) {
            const int gm = bm + wm + i * 16 + kq * 4 + r;
            #pragma unroll
            for (int j = 0; j < 4; j++) {
                const int gn = bn + wn + j * 16 + rr;
                float v = acc[i][j][r];
                if constexpr (MODE == 0) {
                    int bq = gm / (H * H); int rem = gm - bq * (H * H);
                    int yq = rem / H; int xq = rem - yq * H;
                    outF[(((size_t)bq * Cc + gn) * H + yq) * H + xq] = fmaxf(v + bias[gn], 0.f);
                } else if constexpr (MODE == 2) {
                    float q = fmaxf(v + bias[gn], 0.f);
                    short hs = f2bf(q);
                    outH[(size_t)gm * Ff + gn] = hs;
                    outL[(size_t)gm * Ff + gn] = f2bf(q - bf2f(hs));
                } else {
                    if (gn < N) {
                        int bq = gm / (S * S); int rem = gm - bq * (S * S);
                        int xq = rem / S; int yq = rem - xq * S;
                        outF[((size_t)bq * Oo + gn) * LT + (yq * S + xq + POS)] = v + bias[gn];
                    }
                }
            }
        }
    }
}

// =====================================================================
// conv2: N=6 tiny conv. 32 rows/block, 8 ci-groups, w1 in LDS.
// =====================================================================
__global__ __launch_bounds__(TPB)
void conv2_k(const float* __restrict__ h0, const float* __restrict__ h1,
             const float* __restrict__ w1, float* __restrict__ c2)
{
    __shared__ float wl[6][KC];
    __shared__ float part[8][32][6];
    const int tid = threadIdx.x;
    for (int i = tid; i < 6 * KC; i += TPB) wl[i / KC][i - (i / KC) * KC] = w1[i];
    __syncthreads();
    const int row = blockIdx.x * 32 + (tid & 31);
    const int cig = tid >> 5;
    const float* hsrc; int H, S, loc;
    if (row < N0) { hsrc = h0; H = H0; S = S0; loc = row; }
    else          { hsrc = h1; H = H1; S = S1; loc = row - N0; }
    int SS = S * S;
    int b = loc / SS; int rem = loc - b * SS;
    int xq = rem / S; int yq = rem - xq * S;
    float acc[6] = {};
    for (int ci = cig * 32; ci < cig * 32 + 32; ci++) {
        const float* hp = hsrc + ((size_t)(b * Cc + ci) * H + yq) * H + xq;
        #pragma unroll
        for (int ky = 0; ky < 3; ky++)
            #pragma unroll
            for (int kx = 0; kx < 3; kx++) {
                float a = hp[ky * H + kx];
                int kk = ci * 9 + ky * 3 + kx;
                #pragma unroll
                for (int n = 0; n < 6; n++) acc[n] = fmaf(a, wl[n][kk], acc[n]);
            }
    }
    #pragma unroll
    for (int n = 0; n < 6; n++) part[cig][tid & 31][n] = acc[n];
    __syncthreads();
    if (cig == 0) {
        #pragma unroll
        for (int n = 0; n < 6; n++) {
            float s = 0.f;
            for (int g = 0; g < 8; g++) s += part[g][tid & 31][n];
            c2[(size_t)row * 6 + n] = s;
        }
    }
}

// ====================================================================
// theta / theta_diff / sampling coords (verified rounds 1-4)
// ====================================================================
__global__ __launch_bounds__(TPB)
void theta_aux_k(const float* __restrict__ c2, const int* __restrict__ checkp,
                 float* __restrict__ td, float* __restrict__ gxy)
{
    int n = blockIdx.x * TPB + threadIdx.x;
    if (n >= NT_ALL) return;
    float omc = 1.0f - (float)checkp[0];
    const float I[6] = {1.f, 0.f, 0.f, 0.f, 1.f, 0.f};
    float th[6];
    #pragma unroll
    for (int i = 0; i < 6; i++) {
        float v = c2[(size_t)n * 6 + i] * omc + I[i];
        th[i] = v;
        td[(size_t)n * 6 + i] = I[i] - v;
    }
    int S, loc;
    if (n < N0) { S = S0; loc = n; } else { S = S1; loc = n - N0; }
    int SS = S * S;
    int rem = loc % SS;
    int xx = rem / S, yy = rem % S;
    #pragma unroll
    for (int ky = 0; ky < 3; ky++)
        #pragma unroll
        for (int kx = 0; kx < 3; kx++) {
            float bx = (float)(kx - 1), by = (float)(ky - 1);
            gxy[(size_t)n * 18 + ky * 3 + kx]     = th[0] * bx + th[1] * by + th[2] + 1.0f + (float)xx;
            gxy[(size_t)n * 18 + 9 + ky * 3 + kx] = th[3] * bx + th[4] * by + th[5] + 1.0f + (float)yy;
        }
}

__global__ __launch_bounds__(TPB)
void softstats_k(const float* __restrict__ sc, float* __restrict__ mx, float* __restrict__ sm)
{
    int b = blockIdx.x, tid = threadIdx.x;
    const float* p = sc + (size_t)b * Oo * LT;
    constexpr int PER = Oo * LT;
    __shared__ float red[TPB];
    float m = -3.4e38f;
    for (int i = tid; i < PER; i += TPB) m = fmaxf(m, p[i]);
    red[tid] = m;
    for (int off = 128; off; off >>= 1) { __syncthreads(); if (tid < off) red[tid] = fmaxf(red[tid], red[tid + off]); }
    __syncthreads();
    m = red[0];
    __syncthreads();
    float s = 0.f;
    for (int i = tid; i < PER; i += TPB) s += expf(p[i] - m);
    red[tid] = s;
    for (int off = 128; off; off >>= 1) { __syncthreads(); if (tid < off) red[tid] += red[tid + off]; }
    __syncthreads();
    if (tid == 0) { mx[b] = m; sm[b] = red[0]; }
}

__global__ __launch_bounds__(TPB)
void lik_k(const float* __restrict__ sc, const float* __restrict__ mx,
           const float* __restrict__ sm, float* __restrict__ lik)
{
    int b = blockIdx.x, o = threadIdx.x;
    if (o >= Oo) return;
    const float* p = sc + ((size_t)b * Oo + o) * LT;
    float m = mx[b];
    float s = 0.f;
    for (int i = 0; i < LT; i++) s += expf(p[i] - m);
    lik[b * Oo + o] = s / sm[b];
}

__global__ __launch_bounds__(TPB)
void box_k(const float* __restrict__ sc, const float* __restrict__ lik,
           const float* __restrict__ mx, const float* __restrict__ sm,
           const float* __restrict__ gxy, const int* __restrict__ imdp,
           float* __restrict__ boxes, float* __restrict__ boxesNT,
           float* __restrict__ regpart)
{
    int b = blockIdx.x, tid = threadIdx.x;
    __shared__ float sv[TPB];
    __shared__ int si[TPB];

    float v = (tid < Oo) ? lik[b * Oo + tid] : -3.4e38f;
    sv[tid] = v; si[tid] = tid;
    for (int off = 128; off; off >>= 1) {
        __syncthreads();
        if (tid < off) {
            float v2 = sv[tid + off]; int i2 = si[tid + off];
            if (v2 > sv[tid] || (v2 == sv[tid] && i2 < si[tid])) { sv[tid] = v2; si[tid] = i2; }
        }
    }
    __syncthreads();
    int pred = si[0];
    __syncthreads();

    const float* p = sc + ((size_t)b * Oo + pred) * LT;
    float b5 = -3.4e38f; int i5 = 1 << 30;
    float b4 = -3.4e38f; int i4 = 1 << 30;
    for (int pos = tid; pos < LT; pos += TPB) {
        float s = p[pos];
        if (pos < L5) { if (s > b5) { b5 = s; i5 = pos; } }
        else { int q = pos - L5; if (s > b4) { b4 = s; i4 = q; } }
    }
    sv[tid] = b5; si[tid] = i5;
    for (int off = 128; off; off >>= 1) {
        __syncthreads();
        if (tid < off) {
            float v2 = sv[tid + off]; int i2 = si[tid + off];
            if (v2 > sv[tid] || (v2 == sv[tid] && i2 < si[tid])) { sv[tid] = v2; si[tid] = i2; }
        }
    }
    __syncthreads();
    float m5 = sv[0]; int d5 = si[0];
    __syncthreads();
    sv[tid] = b4; si[tid] = i4;
    for (int off = 128; off; off >>= 1) {
        __syncthreads();
        if (tid < off) {
            float v2 = sv[tid + off]; int i2 = si[tid + off];
            if (v2 > sv[tid] || (v2 == sv[tid] && i2 < si[tid])) { sv[tid] = v2; si[tid] = i2; }
        }
    }
    __syncthreads();
    float m4 = sv[0]; int d4 = si[0];

    if (tid == 0) {
        float m = mx[b], s = sm[b];
        float conf5 = expf(m5 - m) / s;
        float conf4 = expf(m4 - m) / s;
        float imd = (float)imdp[0];
        float lo = 0.f, hi = imd - 1.f;

        int xx5 = d5 % S0, yy5 = d5 / S0;
        int n5 = b * (S0 * S0) + xx5 * S0 + yy5;
        const float* g = gxy + (size_t)n5 * 18;
        float txm = 1e30f, txM = -1e30f, tym = 1e30f, tyM = -1e30f;
        for (int j = 0; j < 9; j++) {
            float tx = g[j] / 9.f, ty = g[9 + j] / 9.f;
            txm = fminf(txm, tx); txM = fmaxf(txM, tx);
            tym = fminf(tym, ty); tyM = fmaxf(tyM, ty);
        }
        float box5[5] = { clampf(txm * imd, lo, hi), clampf(tym * imd, lo, hi),
                          clampf(txM * imd, lo, hi), clampf(tyM * imd, lo, hi), conf5 };
        float nt5[5]  = { clampf((float)xx5 / 9.f * imd, lo, hi), clampf((float)yy5 / 9.f * imd, lo, hi),
                          clampf((float)(xx5 + 2) / 9.f * imd, lo, hi), clampf((float)(yy5 + 2) / 9.f * imd, lo, hi), conf5 };

        int xx4 = d4 % S1, yy4 = d4 / S1;
        int n4 = N0 + b * (S1 * S1) + xx4 * S1 + yy4;
        const float* g4 = gxy + (size_t)n4 * 18;
        float txm4 = 1e30f, txM4 = -1e30f, tym4 = 1e30f, tyM4 = -1e30f;
        for (int j = 0; j < 9; j++) {
            float tx = g4[j] / 19.f, ty = g4[9 + j] / 19.f;
            txm4 = fminf(txm4, tx); txM4 = fmaxf(txM4, tx);
            tym4 = fminf(tym4, ty); tyM4 = fmaxf(tyM4, ty);
        }
        float box4[5] = { clampf(txm4 * imd, lo, hi), clampf(tym4 * imd, lo, hi),
                          clampf(txM4 * imd, lo, hi), clampf(tyM4 * imd, lo, hi), conf4 };
        float nt4[5]  = { clampf((float)xx4 / 19.f * imd, lo, hi), clampf((float)yy4 / 19.f * imd, lo, hi),
                          clampf((float)(xx4 + 2) / 19.f * imd, lo, hi), clampf((float)(yy4 + 2) / 19.f * imd, lo, hi), conf4 };

        int mi = (conf4 > conf5) ? 1 : 0;
        for (int i = 0; i < 5; i++) {
            boxes[b * 5 + i]   = mi ? box4[i] : box5[i];
            boxesNT[b * 5 + i] = mi ? nt4[i] : nt5[i];
        }
        regpart[b] = fmaxf(conf4 - conf5, 0.f);
    }
}

__global__ void reg_k(const float* __restrict__ regpart, float* __restrict__ outreg)
{
    if (threadIdx.x == 0) {
        float s = 0.f;
        for (int b = 0; b < Bb; b++) s += regpart[b];
        outreg[0] = s;
    }
}

__global__ void sentinel_k(float* out, int n)
{
    int i = blockIdx.x * 256 + threadIdx.x;
    if (i < n) out[i] = 12345.0f;
}

extern "C" void kernel_launch(void* const* d_in, const int* in_sizes, int n_in,
                              void* d_out, int out_size, void* d_ws, size_t ws_size,
                              hipStream_t stream)
{
    const float* x0 = (const float*)d_in[0];
    const float* x1 = (const float*)d_in[1];
    const float* w0 = (const float*)d_in[2];
    const float* b0 = (const float*)d_in[3];
    const float* w1 = (const float*)d_in[4];
    const float* cw = (const float*)d_in[5];
    const float* cb = (const float*)d_in[6];
    const float* lw = (const float*)d_in[7];
    const float* lb = (const float*)d_in[8];
    const int* checkp = (const int*)d_in[9];
    const int* imdp   = (const int*)d_in[10];

    if (ws_size < B_END) {
        sentinel_k<<<dim3((out_size + 255) / 256), dim3(256), 0, stream>>>((float*)d_out, out_size);
        return;
    }

    char* wsb = (char*)d_ws;
    short* cwh = (short*)(wsb + B_CWH);
    short* cwl = (short*)(wsb + B_CWL);
    short* w0h = (short*)(wsb + B_W0H);
    short* w0l = (short*)(wsb + B_W0L);
    float* gxy = (float*)(wsb + B_GXY);
    short* lwh = (short*)(wsb + B_LWH);
    short* lwl = (short*)(wsb + B_LWL);
    short* fH  = (short*)(wsb + B_FEATH);
    short* fL  = (short*)(wsb + B_FEATL);
    float* mx  = (float*)(wsb + B_MX);
    float* sm  = (float*)(wsb + B_SM);
    float* rp  = (float*)(wsb + B_RP);
    float* sc  = (float*)(wsb + B_SC);
    float* c2  = (float*)(wsb + B_C2);
    float* h0  = (float*)(wsb + B_H0);
    float* h1  = (float*)(wsb + B_H1);

    float* out   = (float*)d_out;
    float* o_lik = out + O_LIK;
    float* o_box = out + O_BOX;
    float* o_nt  = out + O_NT;
    float* o_td  = out + O_TD;
    float* o_reg = out + O_REG;

    dim3 blk(TPB);

    // weight splits (w0/cw: tap-padded 16, k'=c*16+t; lw natural)
    splitp16_k<<<dim3((int)(SZ_W0P + TPB - 1) / TPB), blk, 0, stream>>>(w0, w0h, w0l, Cc);
    splitp16_k<<<dim3((int)(SZ_CWP + TPB - 1) / TPB), blk, 0, stream>>>(cw, cwh, cwl, Ff);
    split_k   <<<dim3((int)(SZ_LW + TPB - 1) / TPB), blk, 0, stream>>>(lw, lwh, lwl, (int)SZ_LW);

    // conv1 (+bias, relu) -> h fp32, both scales   [grid = (nN, nM)]
    mgemm<0, H0, 1, Bb * H0 * H0, Cc, KP, 0><<<dim3(2, 25), blk, 0, stream>>>(
        x0, nullptr, nullptr, nullptr, w0h, w0l, b0, h0, nullptr, nullptr);
    mgemm<0, H1, 1, Bb * H1 * H1, Cc, KP, 0><<<dim3(2, 100), blk, 0, stream>>>(
        x1, nullptr, nullptr, nullptr, w0h, w0l, b0, h1, nullptr, nullptr);

    // conv2 (6 ch) -> c2
    conv2_k<<<dim3(NT_ALL / 32), blk, 0, stream>>>(h0, h1, w1, c2);

    // theta, theta_diff, sampling coords
    theta_aux_k<<<dim3((NT_ALL + TPB - 1) / TPB), blk, 0, stream>>>(c2, checkp, o_td, gxy);

    // fused bilinear-sample GEMM -> feat hi/lo (clobbers h: dead)
    mgemm<2, H0, S0, N0, Ff, KP, 0><<<dim3(8, 16), blk, 0, stream>>>(
        x0, nullptr, nullptr, gxy, cwh, cwl, cb, nullptr, fH, fL);
    mgemm<2, H1, S1, N1, Ff, KP, 0><<<dim3(8, 81), blk, 0, stream>>>(
        x1, nullptr, nullptr, gxy + (size_t)N0 * 18, cwh, cwl, cb,
        nullptr, fH + (size_t)N0 * Ff, fL + (size_t)N0 * Ff);

    // feat -> scores scatter (sc clobbers cw splits: dead)
    mgemm<3, 1, S0, N0, Oo, Ff, 0><<<dim3(2, 16), blk, 0, stream>>>(
        nullptr, fH, fL, nullptr, lwh, lwl, lb, sc, nullptr, nullptr);
    mgemm<3, 1, S1, N1, Oo, Ff, L5><<<dim3(2, 81), blk, 0, stream>>>(
        nullptr, fH + (size_t)N0 * Ff, fL + (size_t)N0 * Ff, nullptr, lwh, lwl, lb,
        sc, nullptr, nullptr);

    // softmax stats, likelihood, boxes, reg
    softstats_k<<<dim3(Bb), blk, 0, stream>>>(sc, mx, sm);
    lik_k<<<dim3(Bb), blk, 0, stream>>>(sc, mx, sm, o_lik);
    box_k<<<dim3(Bb), blk, 0, stream>>>(sc, o_lik, mx, sm, gxy, imdp, o_box, o_nt, rp);
    reg_k<<<dim3(1), dim3(64), 0, stream>>>(rp, o_reg);
}

// Round 6
// 1929.719 us; speedup vs baseline: 1.5201x; 1.5201x over previous
//
#include <hip/hip_runtime.h>
#include <cmath>

#define TPB 256

// ---- problem constants (fixed by setup_inputs) ----
constexpr int Bb = 32, Cc = 256, Ff = 1024, Oo = 201;
constexpr int H0 = 10, S0 = 8,  N0 = Bb * S0 * S0;   // 2048
constexpr int H1 = 20, S1 = 18, N1 = Bb * S1 * S1;   // 10368
constexpr int NT_ALL = N0 + N1;                      // 12416
constexpr int KC = Cc * 9;                           // 2304 (natural K)
constexpr int KP = Cc * 16;                          // 4096 (tap-padded: k' = c*16 + t, taps 9..15 zero)
constexpr int L5 = S0 * S0;                          // 64
constexpr int L4 = S1 * S1;                          // 324
constexpr int LT = L5 + L4;                          // 388

// ---- element counts ----
constexpr size_t SZ_CWP = (size_t)Ff * KP;      // 4,194,304
constexpr size_t SZ_W0P = (size_t)Cc * KP;      // 1,048,576
constexpr size_t SZ_LW  = (size_t)Oo * Ff;      // 205,824
constexpr size_t NFEAT  = (size_t)NT_ALL * Ff;  // 12,713,984

// ---- workspace byte offsets (time-disjoint aliasing) ----
constexpr size_t B_CWH   = 0;
constexpr size_t B_CWL   = B_CWH + SZ_CWP * 2;
constexpr size_t B_W0H   = B_CWL + SZ_CWP * 2;
constexpr size_t B_W0L   = B_W0H + SZ_W0P * 2;
constexpr size_t B_GXY   = B_W0L + SZ_W0P * 2;
constexpr size_t B_LWH   = B_GXY + (size_t)NT_ALL * 18 * 4;
constexpr size_t B_LWL   = B_LWH + SZ_LW * 2;
constexpr size_t B_FEATH = B_LWL + SZ_LW * 2;
constexpr size_t B_FEATL = B_FEATH + NFEAT * 2;
constexpr size_t B_MX    = B_FEATL + NFEAT * 2;          // ~73.5 MB
constexpr size_t B_SM    = B_MX + 128;
constexpr size_t B_RP    = B_SM + 128;
constexpr size_t B_END   = B_RP + 128;
// aliases (disjoint lifetimes):
constexpr size_t B_SC = B_CWH;    // sc over dead cw splits
constexpr size_t B_C2 = B_W0H;    // c2 over dead w0 splits
constexpr size_t B_H0 = B_FEATH;  // h over not-yet-written feat
constexpr size_t B_H1 = B_H0 + (size_t)Bb * Cc * H0 * H0 * 4;

// ---- output layout (floats) ----
constexpr size_t O_LIK = 0;
constexpr size_t O_BOX = O_LIK + Bb * Oo;
constexpr size_t O_NT  = O_BOX + Bb * 5;
constexpr size_t O_TD  = O_NT + Bb * 5;
constexpr size_t O_REG = O_TD + (size_t)NT_ALL * 6;

typedef __attribute__((ext_vector_type(8))) short bf16x8;
typedef __attribute__((ext_vector_type(4))) float f32x4;

// truncation split: v = hi + rem exactly at split point; lo = trunc(rem).
// residual after (hi + lo) <= 2^-16 |v|; dropped lo*lo term <= 2^-16 rel.
__device__ __forceinline__ void tsplit(float v, short& h, short& l) {
    unsigned u = __builtin_bit_cast(unsigned, v);
    h = (short)(u >> 16);
    float hf = __builtin_bit_cast(float, u & 0xffff0000u);
    float r = v - hf;                       // exact
    l = (short)(__builtin_bit_cast(unsigned, r) >> 16);
}
__device__ __forceinline__ float clampf(float x, float lo, float hi) {
    return fminf(fmaxf(x, lo), hi);
}

// =====================================================================
// weight split kernels: fp32 -> (hi, lo) bf16 (truncation split).
// splitp16: src k = c*9 + t  ->  dst k' = c*16 + t,  taps 9..15 = 0
// =====================================================================
__global__ __launch_bounds__(TPB)
void splitp16_k(const float* __restrict__ src, short* __restrict__ hi,
                short* __restrict__ lo, int nrows)
{
    int idx = blockIdx.x * TPB + threadIdx.x;
    if (idx >= nrows * KP) return;
    int row = idx >> 12, kq = idx & (KP - 1);
    int c = kq >> 4, t = kq & 15;
    float v = (t < 9) ? src[(size_t)row * KC + c * 9 + t] : 0.f;
    short h, l; tsplit(v, h, l);
    hi[idx] = h; lo[idx] = l;
}

__global__ __launch_bounds__(TPB)
void split_k(const float* __restrict__ src, short* __restrict__ hi,
             short* __restrict__ lo, int n)
{
    int idx = blockIdx.x * TPB + threadIdx.x;
    if (idx >= n) return;
    short h, l; tsplit(src[idx], h, l);
    hi[idx] = h; lo[idx] = l;
}

// =====================================================================
// Split-bf16 MFMA GEMM: out(MxN) = A(MxK) * Bw(NxK)^T (+bias, act)
// Block 128x128, BK=32, 4 waves, mfma_f32_16x16x32_bf16, 3 MFMAs/pair.
// MODE 0/2: K tap-padded (k=c*16+t); per step channels {c0,c0+1} live in
//   a DOUBLE-BUFFERED LDS slab (issue-early loads hide HBM/L3 latency).
//   A gathered from slab via per-row tap tables (regs, compile-time idx).
//   MODE 2 uses separable bilinear with folded edge weights: per tap
//   reads sp[o],sp[o+1],sp[o+H],sp[o+H+1] (pairs fuse to ds_read2_b32);
//   overreads land in finite staged data / zeroed pad (weight = 0).
// MODE 0: A = im2col pad=1; epilogue relu fp32 -> h
// MODE 2: A = bilinear sample at gxy; epilogue feat hi/lo bf16
// MODE 3: A = pre-split rows (natural K); epilogue score scatter
// GRID: dim3(nN, nM) -- n fastest; nN | 8 pins each XCD to one B-strip.
// =====================================================================
template<int MODE, int H, int S, int M, int N, int KD, int POS>
__global__ __launch_bounds__(TPB, 3)
void mgemm(const float* __restrict__ Asrc,
           const short* __restrict__ AsrcH, const short* __restrict__ AsrcL,
           const float* __restrict__ gxy,
           const short* __restrict__ Bh, const short* __restrict__ Bl,
           const float* __restrict__ bias,
           float* __restrict__ outF, short* __restrict__ outH, short* __restrict__ outL)
{
    constexpr int PLSZ = H * H;                       // plane floats
    constexpr int UPP  = PLSZ / 4;                    // float4 units per plane
    constexpr int RPI  = (MODE == 0) ? H * H : S * S; // rows per image
    constexpr int NBI  = (MODE == 3) ? 1 : (127 / RPI + 2);
    constexpr int SLAB = NBI * 2 * PLSZ + 32;         // +pad for o+H+1 overread

    __shared__ short As[2][4][128][8];   // 16KB
    __shared__ short Bs[2][4][128][8];   // 16KB
    __shared__ float slab[(MODE == 3) ? 1 : 2 * SLAB];

    const int tid = threadIdx.x;
    const int lane = tid & 63;
    const int wid = tid >> 6;
    const int wm = (wid >> 1) * 64, wn = (wid & 1) * 64;
    const int ml = tid & 127, kg0 = tid >> 7;
    const int bm = blockIdx.y * 128, bn = blockIdx.x * 128;   // n fastest

    f32x4 acc[4][4];
    #pragma unroll
    for (int i = 0; i < 4; i++)
        #pragma unroll
        for (int j = 0; j < 4; j++)
            acc[i][j] = (f32x4){0.f, 0.f, 0.f, 0.f};

    const int mG = bm + ml;
    const int nG = bn + ml;

    // ---- per-row tap tables (compile-time indexed => registers) ----
    int bat0 = 0, batidx = 0, nb = 1, nu = 0;
    float wvt[9];  int offt[9];                    // MODE 0
    float wTL[9], wTR[9], wBL[9], wBR[9]; int oTt[9];  // MODE 2

    if constexpr (MODE == 0) {
        bat0 = bm / RPI;
        nb = (bm + 127) / RPI - bat0 + 1;
        nu = nb * 2 * UPP;
        int bA = mG / RPI; int rem = mG - bA * RPI;
        int yA = rem / H, xA = rem - (rem / H) * H;
        batidx = bA - bat0;
        #pragma unroll
        for (int t = 0; t < 9; t++) {
            int ky = t / 3 - 1, kx = t - (t / 3) * 3 - 1;
            int yy = yA + ky, xx = xA + kx;
            bool ok = (yy >= 0 && yy < H && xx >= 0 && xx < H);
            offt[t] = ok ? (yy * H + xx) : 0;
            wvt[t] = ok ? 1.f : 0.f;
        }
    } else if constexpr (MODE == 2) {
        bat0 = bm / RPI;
        nb = (bm + 127) / RPI - bat0 + 1;
        nu = nb * 2 * UPP;
        int bA = mG / RPI;
        batidx = bA - bat0;
        #pragma unroll
        for (int t = 0; t < 9; t++) {
            float gx = gxy[(size_t)mG * 18 + t];
            float gy = gxy[(size_t)mG * 18 + 9 + t];
            float xf = floorf(gx), yf = floorf(gy);
            float wx = gx - xf, wy = gy - yf;
            int ix = (int)xf, iy = (int)yf;
            int cx0 = min(max(ix, 0), H - 1);
            int cy0 = min(max(iy, 0), H - 1);
            bool vx0 = (ix >= 0 && ix < H), vx1 = (ix >= -1 && ix < H - 1);
            bool vy0 = (iy >= 0 && iy < H), vy1 = (iy >= -1 && iy < H - 1);
            // folded separable weights (edge cases collapse into L slot)
            float wxL = vx0 ? (1.f - wx) : (vx1 ? wx : 0.f);
            float wxR = (vx0 && vx1) ? wx : 0.f;
            float wyT = vy0 ? (1.f - wy) : (vy1 ? wy : 0.f);
            float wyB = (vy0 && vy1) ? wy : 0.f;
            wTL[t] = wyT * wxL; wTR[t] = wyT * wxR;
            wBL[t] = wyB * wxL; wBR[t] = wyB * wxR;
            oTt[t] = cy0 * H + cx0;
        }
    }

    // ---- slab double-buffer prefetch machinery ----
    float4 pre[2] = {}, pre2[2] = {};
    auto issue_loads = [&](int c0, float4* dst) {
        #pragma unroll
        for (int q = 0; q < 2; q++) {
            int i = tid + q * TPB;
            if (i < nu) {
                int pl = i / UPP, u = i - pl * UPP;
                int bi = pl >> 1, cc = pl & 1;
                dst[q] = *(const float4*)(Asrc +
                    ((size_t)(bat0 + bi) * Cc + c0 + cc) * PLSZ + u * 4);
            }
        }
    };
    auto write_slab = [&](int cur, const float4* src) {
        #pragma unroll
        for (int q = 0; q < 2; q++) {
            int i = tid + q * TPB;
            if (i < nu) *(float4*)&slab[cur * SLAB + i * 4] = src[q];
        }
    };

    if constexpr (MODE != 3) {
        if (tid < 64) slab[(tid >> 5) * SLAB + nb * 2 * PLSZ + (tid & 31)] = 0.f;
        issue_loads(0, pre);
    }

    int cur = 0;
    for (int kb = 0; kb < KD; kb += 32) {
        if constexpr (MODE != 3) write_slab(cur, pre);
        __syncthreads();
        if constexpr (MODE != 3) {
            if (kb + 32 < KD) issue_loads((kb >> 4) + 2, pre2);
        }
        // ---- B prefetch into regs (global loads issue before gather) ----
        bf16x8 bh0 = {}, bl0 = {}, bh1 = {}, bl1 = {};
        if (nG < N) {
            const size_t bb = (size_t)nG * KD + kb;
            bh0 = *(const bf16x8*)(Bh + bb + (kg0 * 2) * 8);
            bl0 = *(const bf16x8*)(Bl + bb + (kg0 * 2) * 8);
            bh1 = *(const bf16x8*)(Bh + bb + (kg0 * 2 + 1) * 8);
            bl1 = *(const bf16x8*)(Bl + bb + (kg0 * 2 + 1) * 8);
        }
        // ---- A stage ----
        if constexpr (MODE == 0) {
            const float* sp = &slab[cur * SLAB + (batidx * 2 + kg0) * PLSZ];
            bf16x8 hv, lv;
            #pragma unroll
            for (int e = 0; e < 8; e++) {
                float v = sp[offt[e]] * wvt[e];
                short h, l; tsplit(v, h, l); hv[e] = h; lv[e] = l;
            }
            *(bf16x8*)&As[0][kg0 * 2][ml][0] = hv;
            *(bf16x8*)&As[1][kg0 * 2][ml][0] = lv;
            bf16x8 hv2 = {}, lv2 = {};
            { float v = sp[offt[8]] * wvt[8];
              short h, l; tsplit(v, h, l); hv2[0] = h; lv2[0] = l; }
            *(bf16x8*)&As[0][kg0 * 2 + 1][ml][0] = hv2;
            *(bf16x8*)&As[1][kg0 * 2 + 1][ml][0] = lv2;
        } else if constexpr (MODE == 2) {
            const float* sp = &slab[cur * SLAB + (batidx * 2 + kg0) * PLSZ];
            bf16x8 hv, lv;
            #pragma unroll
            for (int e = 0; e < 8; e++) {
                int o = oTt[e];
                float v = sp[o]         * wTL[e] + sp[o + 1]     * wTR[e]
                        + sp[o + H]     * wBL[e] + sp[o + H + 1] * wBR[e];
                short h, l; tsplit(v, h, l); hv[e] = h; lv[e] = l;
            }
            *(bf16x8*)&As[0][kg0 * 2][ml][0] = hv;
            *(bf16x8*)&As[1][kg0 * 2][ml][0] = lv;
            bf16x8 hv2 = {}, lv2 = {};
            { int o = oTt[8];
              float v = sp[o]         * wTL[8] + sp[o + 1]     * wTR[8]
                      + sp[o + H]     * wBL[8] + sp[o + H + 1] * wBR[8];
              short h, l; tsplit(v, h, l); hv2[0] = h; lv2[0] = l; }
            *(bf16x8*)&As[0][kg0 * 2 + 1][ml][0] = hv2;
            *(bf16x8*)&As[1][kg0 * 2 + 1][ml][0] = lv2;
        } else { // MODE 3
            #pragma unroll
            for (int hh = 0; hh < 2; hh++) {
                int kg = kg0 * 2 + hh;
                *(bf16x8*)&As[0][kg][ml][0] = *(const bf16x8*)(AsrcH + (size_t)mG * KD + kb + kg * 8);
                *(bf16x8*)&As[1][kg][ml][0] = *(const bf16x8*)(AsrcL + (size_t)mG * KD + kb + kg * 8);
            }
        }
        // ---- Bs stores ----
        *(bf16x8*)&Bs[0][kg0 * 2][ml][0]     = bh0;
        *(bf16x8*)&Bs[1][kg0 * 2][ml][0]     = bl0;
        *(bf16x8*)&Bs[0][kg0 * 2 + 1][ml][0] = bh1;
        *(bf16x8*)&Bs[1][kg0 * 2 + 1][ml][0] = bl1;
        __syncthreads();
        // ---- MFMA ----
        {
            const int kq = lane >> 4, r = lane & 15;
            bf16x8 ah[4], al[4], bhf[4], blf[4];
            #pragma unroll
            for (int i = 0; i < 4; i++) {
                ah[i]  = *(const bf16x8*)&As[0][kq][wm + i * 16 + r][0];
                al[i]  = *(const bf16x8*)&As[1][kq][wm + i * 16 + r][0];
                bhf[i] = *(const bf16x8*)&Bs[0][kq][wn + i * 16 + r][0];
                blf[i] = *(const bf16x8*)&Bs[1][kq][wn + i * 16 + r][0];
            }
            #pragma unroll
            for (int i = 0; i < 4; i++)
                #pragma unroll
                for (int j = 0; j < 4; j++) {
                    acc[i][j] = __builtin_amdgcn_mfma_f32_16x16x32_bf16(ah[i], bhf[j], acc[i][j], 0, 0, 0);
                    acc[i][j] = __builtin_amdgcn_mfma_f32_16x16x32_bf16(al[i], bhf[j], acc[i][j], 0, 0, 0);
                    acc[i][j] = __builtin_amdgcn_mfma_f32_16x16x32_bf16(ah[i], blf[j], acc[i][j], 0, 0, 0);
                }
        }
        if constexpr (MODE != 3) { pre[0] = pre2[0]; pre[1] = pre2[1]; }
        cur ^= 1;
    }

    // ---------- epilogue ----------
    const int kq = lane >> 4, rr = lane & 15;
    #pragma unroll
    for (int i = 0; i < 4; i++) {
        #pragma unroll
        for (int r = 0; r < 4; r++) {
            const int gm = bm + wm + i * 16 + kq * 4 + r;
            #pragma unroll
            for (int j = 0; j < 4; j++) {
                const int gn = bn + wn + j * 16 + rr;
                float v = acc[i][j][r];
                if constexpr (MODE == 0) {
                    int bq = gm / (H * H); int rem = gm - bq * (H * H);
                    int yq = rem / H; int xq = rem - yq * H;
                    outF[(((size_t)bq * Cc + gn) * H + yq) * H + xq] = fmaxf(v + bias[gn], 0.f);
                } else if constexpr (MODE == 2) {
                    float q = fmaxf(v + bias[gn], 0.f);
                    short h, l; tsplit(q, h, l);
                    outH[(size_t)gm * Ff + gn] = h;
                    outL[(size_t)gm * Ff + gn] = l;
                } else {
                    if (gn < N) {
                        int bq = gm / (S * S); int rem = gm - bq * (S * S);
                        int xq = rem / S; int yq = rem - xq * S;
                        outF[((size_t)bq * Oo + gn) * LT + (yq * S + xq + POS)] = v + bias[gn];
                    }
                }
            }
        }
    }
}

// =====================================================================
// conv2: N=6 tiny conv. 32 rows/block, 8 ci-groups, w1 in LDS.
// =====================================================================
__global__ __launch_bounds__(TPB)
void conv2_k(const float* __restrict__ h0, const float* __restrict__ h1,
             const float* __restrict__ w1, float* __restrict__ c2)
{
    __shared__ float wl[6][KC];
    __shared__ float part[8][32][6];
    const int tid = threadIdx.x;
    for (int i = tid; i < 6 * KC; i += TPB) wl[i / KC][i - (i / KC) * KC] = w1[i];
    __syncthreads();
    const int row = blockIdx.x * 32 + (tid & 31);
    const int cig = tid >> 5;
    const float* hsrc; int H, S, loc;
    if (row < N0) { hsrc = h0; H = H0; S = S0; loc = row; }
    else          { hsrc = h1; H = H1; S = S1; loc = row - N0; }
    int SS = S * S;
    int b = loc / SS; int rem = loc - b * SS;
    int xq = rem / S; int yq = rem - xq * S;
    float acc[6] = {};
    for (int ci = cig * 32; ci < cig * 32 + 32; ci++) {
        const float* hp = hsrc + ((size_t)(b * Cc + ci) * H + yq) * H + xq;
        #pragma unroll
        for (int ky = 0; ky < 3; ky++)
            #pragma unroll
            for (int kx = 0; kx < 3; kx++) {
                float a = hp[ky * H + kx];
                int kk = ci * 9 + ky * 3 + kx;
                #pragma unroll
                for (int n = 0; n < 6; n++) acc[n] = fmaf(a, wl[n][kk], acc[n]);
            }
    }
    #pragma unroll
    for (int n = 0; n < 6; n++) part[cig][tid & 31][n] = acc[n];
    __syncthreads();
    if (cig == 0) {
        #pragma unroll
        for (int n = 0; n < 6; n++) {
            float s = 0.f;
            for (int g = 0; g < 8; g++) s += part[g][tid & 31][n];
            c2[(size_t)row * 6 + n] = s;
        }
    }
}

// ====================================================================
// theta / theta_diff / sampling coords (verified rounds 1-5)
// ====================================================================
__global__ __launch_bounds__(TPB)
void theta_aux_k(const float* __restrict__ c2, const int* __restrict__ checkp,
                 float* __restrict__ td, float* __restrict__ gxy)
{
    int n = blockIdx.x * TPB + threadIdx.x;
    if (n >= NT_ALL) return;
    float omc = 1.0f - (float)checkp[0];
    const float I[6] = {1.f, 0.f, 0.f, 0.f, 1.f, 0.f};
    float th[6];
    #pragma unroll
    for (int i = 0; i < 6; i++) {
        float v = c2[(size_t)n * 6 + i] * omc + I[i];
        th[i] = v;
        td[(size_t)n * 6 + i] = I[i] - v;
    }
    int S, loc;
    if (n < N0) { S = S0; loc = n; } else { S = S1; loc = n - N0; }
    int SS = S * S;
    int rem = loc % SS;
    int xx = rem / S, yy = rem % S;
    #pragma unroll
    for (int ky = 0; ky < 3; ky++)
        #pragma unroll
        for (int kx = 0; kx < 3; kx++) {
            float bx = (float)(kx - 1), by = (float)(ky - 1);
            gxy[(size_t)n * 18 + ky * 3 + kx]     = th[0] * bx + th[1] * by + th[2] + 1.0f + (float)xx;
            gxy[(size_t)n * 18 + 9 + ky * 3 + kx] = th[3] * bx + th[4] * by + th[5] + 1.0f + (float)yy;
        }
}

__global__ __launch_bounds__(TPB)
void softstats_k(const float* __restrict__ sc, float* __restrict__ mx, float* __restrict__ sm)
{
    int b = blockIdx.x, tid = threadIdx.x;
    const float* p = sc + (size_t)b * Oo * LT;
    constexpr int PER = Oo * LT;
    __shared__ float red[TPB];
    float m = -3.4e38f;
    for (int i = tid; i < PER; i += TPB) m = fmaxf(m, p[i]);
    red[tid] = m;
    for (int off = 128; off; off >>= 1) { __syncthreads(); if (tid < off) red[tid] = fmaxf(red[tid], red[tid + off]); }
    __syncthreads();
    m = red[0];
    __syncthreads();
    float s = 0.f;
    for (int i = tid; i < PER; i += TPB) s += expf(p[i] - m);
    red[tid] = s;
    for (int off = 128; off; off >>= 1) { __syncthreads(); if (tid < off) red[tid] += red[tid + off]; }
    __syncthreads();
    if (tid == 0) { mx[b] = m; sm[b] = red[0]; }
}

__global__ __launch_bounds__(TPB)
void lik_k(const float* __restrict__ sc, const float* __restrict__ mx,
           const float* __restrict__ sm, float* __restrict__ lik)
{
    int b = blockIdx.x, o = threadIdx.x;
    if (o >= Oo) return;
    const float* p = sc + ((size_t)b * Oo + o) * LT;
    float m = mx[b];
    float s = 0.f;
    for (int i = 0; i < LT; i++) s += expf(p[i] - m);
    lik[b * Oo + o] = s / sm[b];
}

__global__ __launch_bounds__(TPB)
void box_k(const float* __restrict__ sc, const float* __restrict__ lik,
           const float* __restrict__ mx, const float* __restrict__ sm,
           const float* __restrict__ gxy, const int* __restrict__ imdp,
           float* __restrict__ boxes, float* __restrict__ boxesNT,
           float* __restrict__ regpart)
{
    int b = blockIdx.x, tid = threadIdx.x;
    __shared__ float sv[TPB];
    __shared__ int si[TPB];

    float v = (tid < Oo) ? lik[b * Oo + tid] : -3.4e38f;
    sv[tid] = v; si[tid] = tid;
    for (int off = 128; off; off >>= 1) {
        __syncthreads();
        if (tid < off) {
            float v2 = sv[tid + off]; int i2 = si[tid + off];
            if (v2 > sv[tid] || (v2 == sv[tid] && i2 < si[tid])) { sv[tid] = v2; si[tid] = i2; }
        }
    }
    __syncthreads();
    int pred = si[0];
    __syncthreads();

    const float* p = sc + ((size_t)b * Oo + pred) * LT;
    float b5 = -3.4e38f; int i5 = 1 << 30;
    float b4 = -3.4e38f; int i4 = 1 << 30;
    for (int pos = tid; pos < LT; pos += TPB) {
        float s = p[pos];
        if (pos < L5) { if (s > b5) { b5 = s; i5 = pos; } }
        else { int q = pos - L5; if (s > b4) { b4 = s; i4 = q; } }
    }
    sv[tid] = b5; si[tid] = i5;
    for (int off = 128; off; off >>= 1) {
        __syncthreads();
        if (tid < off) {
            float v2 = sv[tid + off]; int i2 = si[tid + off];
            if (v2 > sv[tid] || (v2 == sv[tid] && i2 < si[tid])) { sv[tid] = v2; si[tid] = i2; }
        }
    }
    __syncthreads();
    float m5 = sv[0]; int d5 = si[0];
    __syncthreads();
    sv[tid] = b4; si[tid] = i4;
    for (int off = 128; off; off >>= 1) {
        __syncthreads();
        if (tid < off) {
            float v2 = sv[tid + off]; int i2 = si[tid + off];
            if (v2 > sv[tid] || (v2 == sv[tid] && i2 < si[tid])) { sv[tid] = v2; si[tid] = i2; }
        }
    }
    __syncthreads();
    float m4 = sv[0]; int d4 = si[0];

    if (tid == 0) {
        float m = mx[b], s = sm[b];
        float conf5 = expf(m5 - m) / s;
        float conf4 = expf(m4 - m) / s;
        float imd = (float)imdp[0];
        float lo = 0.f, hi = imd - 1.f;

        int xx5 = d5 % S0, yy5 = d5 / S0;
        int n5 = b * (S0 * S0) + xx5 * S0 + yy5;
        const float* g = gxy + (size_t)n5 * 18;
        float txm = 1e30f, txM = -1e30f, tym = 1e30f, tyM = -1e30f;
        for (int j = 0; j < 9; j++) {
            float tx = g[j] / 9.f, ty = g[9 + j] / 9.f;
            txm = fminf(txm, tx); txM = fmaxf(txM, tx);
            tym = fminf(tym, ty); tyM = fmaxf(tyM, ty);
        }
        float box5[5] = { clampf(txm * imd, lo, hi), clampf(tym * imd, lo, hi),
                          clampf(txM * imd, lo, hi), clampf(tyM * imd, lo, hi), conf5 };
        float nt5[5]  = { clampf((float)xx5 / 9.f * imd, lo, hi), clampf((float)yy5 / 9.f * imd, lo, hi),
                          clampf((float)(xx5 + 2) / 9.f * imd, lo, hi), clampf((float)(yy5 + 2) / 9.f * imd, lo, hi), conf5 };

        int xx4 = d4 % S1, yy4 = d4 / S1;
        int n4 = N0 + b * (S1 * S1) + xx4 * S1 + yy4;
        const float* g4 = gxy + (size_t)n4 * 18;
        float txm4 = 1e30f, txM4 = -1e30f, tym4 = 1e30f, tyM4 = -1e30f;
        for (int j = 0; j < 9; j++) {
            float tx = g4[j] / 19.f, ty = g4[9 + j] / 19.f;
            txm4 = fminf(txm4, tx); txM4 = fmaxf(txM4, tx);
            tym4 = fminf(tym4, ty); tyM4 = fmaxf(tyM4, ty);
        }
        float box4[5] = { clampf(txm4 * imd, lo, hi), clampf(tym4 * imd, lo, hi),
                          clampf(txM4 * imd, lo, hi), clampf(tyM4 * imd, lo, hi), conf4 };
        float nt4[5]  = { clampf((float)xx4 / 19.f * imd, lo, hi), clampf((float)yy4 / 19.f * imd, lo, hi),
                          clampf((float)(xx4 + 2) / 19.f * imd, lo, hi), clampf((float)(yy4 + 2) / 19.f * imd, lo, hi), conf4 };

        int mi = (conf4 > conf5) ? 1 : 0;
        for (int i = 0; i < 5; i++) {
            boxes[b * 5 + i]   = mi ? box4[i] : box5[i];
            boxesNT[b * 5 + i] = mi ? nt4[i] : nt5[i];
        }
        regpart[b] = fmaxf(conf4 - conf5, 0.f);
    }
}

__global__ void reg_k(const float* __restrict__ regpart, float* __restrict__ outreg)
{
    if (threadIdx.x == 0) {
        float s = 0.f;
        for (int b = 0; b < Bb; b++) s += regpart[b];
        outreg[0] = s;
    }
}

__global__ void sentinel_k(float* out, int n)
{
    int i = blockIdx.x * 256 + threadIdx.x;
    if (i < n) out[i] = 12345.0f;
}

extern "C" void kernel_launch(void* const* d_in, const int* in_sizes, int n_in,
                              void* d_out, int out_size, void* d_ws, size_t ws_size,
                              hipStream_t stream)
{
    const float* x0 = (const float*)d_in[0];
    const float* x1 = (const float*)d_in[1];
    const float* w0 = (const float*)d_in[2];
    const float* b0 = (const float*)d_in[3];
    const float* w1 = (const float*)d_in[4];
    const float* cw = (const float*)d_in[5];
    const float* cb = (const float*)d_in[6];
    const float* lw = (const float*)d_in[7];
    const float* lb = (const float*)d_in[8];
    const int* checkp = (const int*)d_in[9];
    const int* imdp   = (const int*)d_in[10];

    if (ws_size < B_END) {
        sentinel_k<<<dim3((out_size + 255) / 256), dim3(256), 0, stream>>>((float*)d_out, out_size);
        return;
    }

    char* wsb = (char*)d_ws;
    short* cwh = (short*)(wsb + B_CWH);
    short* cwl = (short*)(wsb + B_CWL);
    short* w0h = (short*)(wsb + B_W0H);
    short* w0l = (short*)(wsb + B_W0L);
    float* gxy = (float*)(wsb + B_GXY);
    short* lwh = (short*)(wsb + B_LWH);
    short* lwl = (short*)(wsb + B_LWL);
    short* fH  = (short*)(wsb + B_FEATH);
    short* fL  = (short*)(wsb + B_FEATL);
    float* mx  = (float*)(wsb + B_MX);
    float* sm  = (float*)(wsb + B_SM);
    float* rp  = (float*)(wsb + B_RP);
    float* sc  = (float*)(wsb + B_SC);
    float* c2  = (float*)(wsb + B_C2);
    float* h0  = (float*)(wsb + B_H0);
    float* h1  = (float*)(wsb + B_H1);

    float* out   = (float*)d_out;
    float* o_lik = out + O_LIK;
    float* o_box = out + O_BOX;
    float* o_nt  = out + O_NT;
    float* o_td  = out + O_TD;
    float* o_reg = out + O_REG;

    dim3 blk(TPB);

    // weight splits (w0/cw: tap-padded 16, k'=c*16+t; lw natural)
    splitp16_k<<<dim3((int)((SZ_W0P + TPB - 1) / TPB)), blk, 0, stream>>>(w0, w0h, w0l, Cc);
    splitp16_k<<<dim3((int)((SZ_CWP + TPB - 1) / TPB)), blk, 0, stream>>>(cw, cwh, cwl, Ff);
    split_k   <<<dim3((int)((SZ_LW + TPB - 1) / TPB)), blk, 0, stream>>>(lw, lwh, lwl, (int)SZ_LW);

    // conv1 (+bias, relu) -> h fp32, both scales   [grid = (nN, nM)]
    mgemm<0, H0, 1, Bb * H0 * H0, Cc, KP, 0><<<dim3(2, 25), blk, 0, stream>>>(
        x0, nullptr, nullptr, nullptr, w0h, w0l, b0, h0, nullptr, nullptr);
    mgemm<0, H1, 1, Bb * H1 * H1, Cc, KP, 0><<<dim3(2, 100), blk, 0, stream>>>(
        x1, nullptr, nullptr, nullptr, w0h, w0l, b0, h1, nullptr, nullptr);

    // conv2 (6 ch) -> c2
    conv2_k<<<dim3(NT_ALL / 32), blk, 0, stream>>>(h0, h1, w1, c2);

    // theta, theta_diff, sampling coords
    theta_aux_k<<<dim3((NT_ALL + TPB - 1) / TPB), blk, 0, stream>>>(c2, checkp, o_td, gxy);

    // fused bilinear-sample GEMM -> feat hi/lo (clobbers h: dead)
    mgemm<2, H0, S0, N0, Ff, KP, 0><<<dim3(8, 16), blk, 0, stream>>>(
        x0, nullptr, nullptr, gxy, cwh, cwl, cb, nullptr, fH, fL);
    mgemm<2, H1, S1, N1, Ff, KP, 0><<<dim3(8, 81), blk, 0, stream>>>(
        x1, nullptr, nullptr, gxy + (size_t)N0 * 18, cwh, cwl, cb,
        nullptr, fH + (size_t)N0 * Ff, fL + (size_t)N0 * Ff);

    // feat -> scores scatter (sc clobbers cw splits: dead)
    mgemm<3, 1, S0, N0, Oo, Ff, 0><<<dim3(2, 16), blk, 0, stream>>>(
        nullptr, fH, fL, nullptr, lwh, lwl, lb, sc, nullptr, nullptr);
    mgemm<3, 1, S1, N1, Oo, Ff, L5><<<dim3(2, 81), blk, 0, stream>>>(
        nullptr, fH + (size_t)N0 * Ff, fL + (size_t)N0 * Ff, nullptr, lwh, lwl, lb,
        sc, nullptr, nullptr);

    // softmax stats, likelihood, boxes, reg
    softstats_k<<<dim3(Bb), blk, 0, stream>>>(sc, mx, sm);
    lik_k<<<dim3(Bb), blk, 0, stream>>>(sc, mx, sm, o_lik);
    box_k<<<dim3(Bb), blk, 0, stream>>>(sc, o_lik, mx, sm, gxy, imdp, o_box, o_nt, rp);
    reg_k<<<dim3(1), dim3(64), 0, stream>>>(rp, o_reg);
}

// Round 7
// 1733.738 us; speedup vs baseline: 1.6919x; 1.1130x over previous
//
#include <hip/hip_runtime.h>
#include <cmath>

#define TPB 256

// ---- problem constants (fixed by setup_inputs) ----
constexpr int Bb = 32, Cc = 256, Ff = 1024, Oo = 201;
constexpr int H0 = 10, S0 = 8,  N0 = Bb * S0 * S0;   // 2048
constexpr int H1 = 20, S1 = 18, N1 = Bb * S1 * S1;   // 10368
constexpr int NT_ALL = N0 + N1;                      // 12416
constexpr int KC = Cc * 9;                           // 2304 (natural K)
constexpr int KP = Cc * 16;                          // 4096 (tap-padded K for conv1 slab path)
constexpr int L5 = S0 * S0;                          // 64
constexpr int L4 = S1 * S1;                          // 324
constexpr int LT = L5 + L4;                          // 388
constexpr int CHUNK = 4096;                          // xs/feat chunk rows

// ---- element counts ----
constexpr size_t SZ_CW  = (size_t)Ff * KC;      // 2,359,296
constexpr size_t SZ_W0P = (size_t)Cc * KP;      // 1,048,576
constexpr size_t SZ_LW  = (size_t)Oo * Ff;      // 205,824

// ---- workspace byte offsets ----
constexpr size_t B_CWH = 0;
constexpr size_t B_CWL = B_CWH + SZ_CW * 2;                 //  4,718,592
constexpr size_t B_GXY = B_CWL + SZ_CW * 2;                 //  9,437,184
constexpr size_t B_LWH = B_GXY + (size_t)NT_ALL * 18 * 4;   // 10,331,136
constexpr size_t B_LWL = B_LWH + SZ_LW * 2;                 // 10,742,784
constexpr size_t B_SC  = B_LWL + SZ_LW * 2;                 // 11,154,432
constexpr size_t B_XSH = B_SC + (size_t)Bb * Oo * LT * 4;   // 21,136,896
constexpr size_t B_XSL = B_XSH + (size_t)CHUNK * KC * 2;    // 40,011,264
constexpr size_t B_FCH = B_XSL + (size_t)CHUNK * KC * 2;    // 58,885,632
constexpr size_t B_FCL = B_FCH + (size_t)CHUNK * Ff * 2;    // 67,274,240
constexpr size_t B_MX  = B_FCL + (size_t)CHUNK * Ff * 2;    // 75,662,848
constexpr size_t B_SM  = B_MX + 128;
constexpr size_t B_RP  = B_SM + 128;
constexpr size_t B_END = B_RP + 128;                        // ~75.7 MB (ws proven >= 78.4 MB)
// aliases (disjoint lifetimes): w0 splits + h live in xs buffers, dead before chunks run
constexpr size_t B_W0H = B_XSH;
constexpr size_t B_W0L = B_XSH + SZ_W0P * 2;                // 4.2 MB total <= 18.9 MB region
constexpr size_t B_H0  = B_XSL;
constexpr size_t B_H1  = B_XSL + (size_t)Bb * Cc * H0 * H0 * 4;  // 16.4 MB total <= 18.9 MB

// ---- output layout (floats) ----
constexpr size_t O_LIK = 0;
constexpr size_t O_BOX = O_LIK + Bb * Oo;
constexpr size_t O_NT  = O_BOX + Bb * 5;
constexpr size_t O_TD  = O_NT + Bb * 5;
constexpr size_t O_REG = O_TD + (size_t)NT_ALL * 6;

typedef __attribute__((ext_vector_type(8))) short bf16x8;
typedef __attribute__((ext_vector_type(4))) float f32x4;

// truncation split: v = hi + r exactly; lo = trunc-to-bf16(r).
__device__ __forceinline__ void tsplit(float v, short& h, short& l) {
    unsigned u = __builtin_bit_cast(unsigned, v);
    h = (short)(u >> 16);
    float hf = __builtin_bit_cast(float, u & 0xffff0000u);
    float r = v - hf;                       // exact
    l = (short)(__builtin_bit_cast(unsigned, r) >> 16);
}
__device__ __forceinline__ float clampf(float x, float lo, float hi) {
    return fminf(fmaxf(x, lo), hi);
}

// =====================================================================
// weight split kernels
// splitp_k : fp32 -> hi/lo, K-permuted k' = t*256 + c  (for cw, matches xs)
// splitp16_k: fp32 -> hi/lo, tap-padded k' = c*16 + t  (for w0, conv1 slab)
// split_k  : plain (lw)
// =====================================================================
__global__ __launch_bounds__(TPB)
void splitp_k(const float* __restrict__ src, short* __restrict__ hi,
              short* __restrict__ lo, int nrows)
{
    int idx = blockIdx.x * TPB + threadIdx.x;
    if (idx >= nrows * KC) return;
    int row = idx / KC, k = idx - row * KC;
    int c = k / 9, t = k - c * 9;
    float v = src[idx];
    short h, l; tsplit(v, h, l);
    size_t dst = (size_t)row * KC + t * 256 + c;
    hi[dst] = h; lo[dst] = l;
}

__global__ __launch_bounds__(TPB)
void splitp16_k(const float* __restrict__ src, short* __restrict__ hi,
                short* __restrict__ lo, int nrows)
{
    int idx = blockIdx.x * TPB + threadIdx.x;
    if (idx >= nrows * KP) return;
    int row = idx >> 12, kq = idx & (KP - 1);
    int c = kq >> 4, t = kq & 15;
    float v = (t < 9) ? src[(size_t)row * KC + c * 9 + t] : 0.f;
    short h, l; tsplit(v, h, l);
    hi[idx] = h; lo[idx] = l;
}

__global__ __launch_bounds__(TPB)
void split_k(const float* __restrict__ src, short* __restrict__ hi,
             short* __restrict__ lo, int n)
{
    int idx = blockIdx.x * TPB + threadIdx.x;
    if (idx >= n) return;
    short h, l; tsplit(src[idx], h, l);
    hi[idx] = h; lo[idx] = l;
}

// =====================================================================
// mat_k: materialize sampled im2col chunk as split bf16 (gather ONCE).
// thread = (mloc, tap j, channel-group cg of 8); k' = j*256 + c.
// Bilinear with folded separable edge weights (round-6-verified math);
// zero-weight corners redirected to the safe base offset (in-plane).
// =====================================================================
__global__ __launch_bounds__(TPB)
void mat_k(const float* __restrict__ x0, const float* __restrict__ x1,
           const float* __restrict__ gxy, short* __restrict__ xsH,
           short* __restrict__ xsL, int base, int rows)
{
    int idx = blockIdx.x * TPB + threadIdx.x;
    if (idx >= rows * 288) return;
    int mloc = idx / 288, r = idx - mloc * 288;
    int j = r >> 5, cg = r & 31;
    int m = base + mloc;
    const float* xp; int H, loc, SS;
    if (m < N0) { xp = x0; H = H0; loc = m; SS = 64; }
    else        { xp = x1; H = H1; loc = m - N0; SS = 324; }
    int b = loc / SS;
    float gx = gxy[(size_t)m * 18 + j];
    float gy = gxy[(size_t)m * 18 + 9 + j];
    float xf = floorf(gx), yf = floorf(gy);
    float wx = gx - xf, wy = gy - yf;
    int ix = (int)xf, iy = (int)yf;
    int cx0 = min(max(ix, 0), H - 1), cy0 = min(max(iy, 0), H - 1);
    bool vx0 = (ix >= 0 && ix < H), vx1 = (ix >= -1 && ix < H - 1);
    bool vy0 = (iy >= 0 && iy < H), vy1 = (iy >= -1 && iy < H - 1);
    float wxL = vx0 ? (1.f - wx) : (vx1 ? wx : 0.f);
    float wxR = (vx0 && vx1) ? wx : 0.f;
    float wyT = vy0 ? (1.f - wy) : (vy1 ? wy : 0.f);
    float wyB = (vy0 && vy1) ? wy : 0.f;
    float wTL = wyT * wxL, wTR = wyT * wxR, wBL = wyB * wxL, wBR = wyB * wxR;
    int o   = cy0 * H + cx0;
    int oTR = (wTR != 0.f) ? o + 1     : o;
    int oBL = (wBL != 0.f) ? o + H     : o;
    int oBR = (wBR != 0.f) ? o + H + 1 : o;
    const float* cp = xp + ((size_t)b * Cc + cg * 8) * (H * H);
    bf16x8 hv, lv;
    #pragma unroll
    for (int e = 0; e < 8; e++) {
        float v = cp[o] * wTL + cp[oTR] * wTR + cp[oBL] * wBL + cp[oBR] * wBR;
        short h, l; tsplit(v, h, l); hv[e] = h; lv[e] = l;
        cp += H * H;
    }
    size_t dst = (size_t)mloc * KC + j * 256 + cg * 8;
    *(bf16x8*)&xsH[dst] = hv;
    *(bf16x8*)&xsL[dst] = lv;
}

// =====================================================================
// Split-bf16 MFMA GEMM: 128x128 block, BK=32, 4 waves, 3 MFMAs/pair.
// MODE 0: conv1 — A = im2col pad=1 from x via single-buffer LDS slab,
//         K tap-padded (k=c*16+t, KD=KP); epilogue relu fp32 -> h.
// MODE 4: A = presplit xs chunk (KD=KC); epilogue feat hi/lo bf16.
// MODE 5: A = presplit feat chunk (KD=Ff); epilogue score scatter with
//         RUNTIME scale split (global row = base + gm).
// GRID: dim3(nN, nM) -- n fastest; nN | 8 pins each XCD to one B-strip.
// =====================================================================
template<int MODE, int H, int N, int KD>
__global__ __launch_bounds__(TPB, 2)
void mgemm(const float* __restrict__ Asrc,
           const short* __restrict__ AsH, const short* __restrict__ AsL,
           const short* __restrict__ Bh, const short* __restrict__ Bl,
           const float* __restrict__ bias,
           float* __restrict__ outF, short* __restrict__ outH, short* __restrict__ outL,
           int base)
{
    constexpr int PLSZ = H * H;
    constexpr int RPI  = H * H;                        // rows per image (MODE 0)
    constexpr int NBI  = (MODE == 0) ? (127 / RPI + 2) : 1;

    __shared__ short As[2][4][128][8];   // 16KB
    __shared__ short Bs[2][4][128][8];   // 16KB
    __shared__ float slab[(MODE == 0) ? NBI * 2 * PLSZ : 1];

    const int tid = threadIdx.x;
    const int lane = tid & 63;
    const int wid = tid >> 6;
    const int wm = (wid >> 1) * 64, wn = (wid & 1) * 64;
    const int ml = tid & 127, kg0 = tid >> 7;
    const int bm = blockIdx.y * 128, bn = blockIdx.x * 128;   // n fastest

    f32x4 acc[4][4];
    #pragma unroll
    for (int i = 0; i < 4; i++)
        #pragma unroll
        for (int j = 0; j < 4; j++)
            acc[i][j] = (f32x4){0.f, 0.f, 0.f, 0.f};

    const int mG = bm + ml;
    const int nG = bn + ml;

    // ---- MODE 0 per-row tap tables (compile-time indexed => registers) ----
    int bat0 = 0, batidx = 0, nb = 1;
    float wvt[9]; int offt[9];
    if constexpr (MODE == 0) {
        bat0 = bm / RPI;
        nb = (bm + 127) / RPI - bat0 + 1;
        int bA = mG / RPI; int rem = mG - bA * RPI;
        int yA = rem / H, xA = rem - (rem / H) * H;
        batidx = bA - bat0;
        #pragma unroll
        for (int t = 0; t < 9; t++) {
            int ky = t / 3 - 1, kx = t - (t / 3) * 3 - 1;
            int yy = yA + ky, xx = xA + kx;
            bool ok = (yy >= 0 && yy < H && xx >= 0 && xx < H);
            offt[t] = ok ? (yy * H + xx) : 0;
            wvt[t] = ok ? 1.f : 0.f;
        }
    }

    for (int kb = 0; kb < KD; kb += 32) {
        // ---------- MODE 0: slab stage (channels c0, c0+1) ----------
        if constexpr (MODE == 0) {
            const int c0 = kb >> 4;
            constexpr int UPP = PLSZ / 4;
            const int nu = nb * 2 * UPP;
            for (int i = tid; i < nu; i += TPB) {
                int pl = i / UPP, u = i - pl * UPP;
                int bi = pl >> 1, cc = pl & 1;
                *(float4*)&slab[pl * PLSZ + u * 4] =
                    *(const float4*)(Asrc + ((size_t)(bat0 + bi) * Cc + c0 + cc) * PLSZ + u * 4);
            }
            __syncthreads();
        }
        // ---------- A stage ----------
        if constexpr (MODE == 0) {
            const float* sp = &slab[(batidx * 2 + kg0) * PLSZ];
            bf16x8 hv, lv;
            #pragma unroll
            for (int e = 0; e < 8; e++) {
                float v = sp[offt[e]] * wvt[e];
                short h, l; tsplit(v, h, l); hv[e] = h; lv[e] = l;
            }
            *(bf16x8*)&As[0][kg0 * 2][ml][0] = hv;
            *(bf16x8*)&As[1][kg0 * 2][ml][0] = lv;
            bf16x8 hv2 = {}, lv2 = {};
            { float v = sp[offt[8]] * wvt[8];
              short h, l; tsplit(v, h, l); hv2[0] = h; lv2[0] = l; }
            *(bf16x8*)&As[0][kg0 * 2 + 1][ml][0] = hv2;
            *(bf16x8*)&As[1][kg0 * 2 + 1][ml][0] = lv2;
        } else {
            #pragma unroll
            for (int hh = 0; hh < 2; hh++) {
                int kg = kg0 * 2 + hh;
                *(bf16x8*)&As[0][kg][ml][0] = *(const bf16x8*)(AsH + (size_t)mG * KD + kb + kg * 8);
                *(bf16x8*)&As[1][kg][ml][0] = *(const bf16x8*)(AsL + (size_t)mG * KD + kb + kg * 8);
            }
        }
        // ---------- B stage ----------
        #pragma unroll
        for (int hh = 0; hh < 2; hh++) {
            int kg = kg0 * 2 + hh;
            bf16x8 hv = {}, lv = {};
            if (nG < N) {
                hv = *(const bf16x8*)(Bh + (size_t)nG * KD + kb + kg * 8);
                lv = *(const bf16x8*)(Bl + (size_t)nG * KD + kb + kg * 8);
            }
            *(bf16x8*)&Bs[0][kg][ml][0] = hv;
            *(bf16x8*)&Bs[1][kg][ml][0] = lv;
        }
        __syncthreads();
        // ---------- MFMA ----------
        {
            const int kq = lane >> 4, r = lane & 15;
            bf16x8 ah[4], al[4], bhf[4], blf[4];
            #pragma unroll
            for (int i = 0; i < 4; i++) {
                ah[i]  = *(const bf16x8*)&As[0][kq][wm + i * 16 + r][0];
                al[i]  = *(const bf16x8*)&As[1][kq][wm + i * 16 + r][0];
                bhf[i] = *(const bf16x8*)&Bs[0][kq][wn + i * 16 + r][0];
                blf[i] = *(const bf16x8*)&Bs[1][kq][wn + i * 16 + r][0];
            }
            #pragma unroll
            for (int i = 0; i < 4; i++)
                #pragma unroll
                for (int j = 0; j < 4; j++) {
                    acc[i][j] = __builtin_amdgcn_mfma_f32_16x16x32_bf16(ah[i], bhf[j], acc[i][j], 0, 0, 0);
                    acc[i][j] = __builtin_amdgcn_mfma_f32_16x16x32_bf16(al[i], bhf[j], acc[i][j], 0, 0, 0);
                    acc[i][j] = __builtin_amdgcn_mfma_f32_16x16x32_bf16(ah[i], blf[j], acc[i][j], 0, 0, 0);
                }
        }
        __syncthreads();
    }

    // ---------- epilogue ----------
    const int kq = lane >> 4, rr = lane & 15;
    #pragma unroll
    for (int i = 0; i < 4; i++) {
        #pragma unroll
        for (int r = 0; r < 4; r++) {
            const int gm = bm + wm + i * 16 + kq * 4 + r;
            #pragma unroll
            for (int j = 0; j < 4; j++) {
                const int gn = bn + wn + j * 16 + rr;
                float v = acc[i][j][r];
                if constexpr (MODE == 0) {
                    int bq = gm / (H * H); int rem = gm - bq * (H * H);
                    int yq = rem / H; int xq = rem - yq * H;
                    outF[(((size_t)bq * Cc + gn) * H + yq) * H + xq] = fmaxf(v + bias[gn], 0.f);
                } else if constexpr (MODE == 4) {
                    float q = fmaxf(v + bias[gn], 0.f);
                    short h, l; tsplit(q, h, l);
                    outH[(size_t)gm * Ff + gn] = h;
                    outL[(size_t)gm * Ff + gn] = l;
                } else { // MODE 5: score scatter, runtime scale split
                    if (gn < N) {
                        int g = base + gm;
                        int bq, pos;
                        if (g < N0) {
                            int lo = g & 63; bq = g >> 6;
                            pos = (lo & 7) * 8 + (lo >> 3);
                        } else {
                            int gg = g - N0; bq = gg / 324; int lo = gg - bq * 324;
                            int xq = lo / 18, yq = lo - xq * 18;
                            pos = L5 + yq * 18 + xq;
                        }
                        outF[((size_t)bq * Oo + gn) * LT + pos] = v + bias[gn];
                    }
                }
            }
        }
    }
}

// =====================================================================
// conv2: N=6 tiny conv. 32 rows/block, 8 ci-groups, w1 in LDS.
// =====================================================================
__global__ __launch_bounds__(TPB)
void conv2_k(const float* __restrict__ h0, const float* __restrict__ h1,
             const float* __restrict__ w1, float* __restrict__ c2)
{
    __shared__ float wl[6][KC];
    __shared__ float part[8][32][6];
    const int tid = threadIdx.x;
    for (int i = tid; i < 6 * KC; i += TPB) wl[i / KC][i - (i / KC) * KC] = w1[i];
    __syncthreads();
    const int row = blockIdx.x * 32 + (tid & 31);
    const int cig = tid >> 5;
    const float* hsrc; int H, S, loc;
    if (row < N0) { hsrc = h0; H = H0; S = S0; loc = row; }
    else          { hsrc = h1; H = H1; S = S1; loc = row - N0; }
    int SS = S * S;
    int b = loc / SS; int rem = loc - b * SS;
    int xq = rem / S; int yq = rem - xq * S;
    float acc[6] = {};
    for (int ci = cig * 32; ci < cig * 32 + 32; ci++) {
        const float* hp = hsrc + ((size_t)(b * Cc + ci) * H + yq) * H + xq;
        #pragma unroll
        for (int ky = 0; ky < 3; ky++)
            #pragma unroll
            for (int kx = 0; kx < 3; kx++) {
                float a = hp[ky * H + kx];
                int kk = ci * 9 + ky * 3 + kx;
                #pragma unroll
                for (int n = 0; n < 6; n++) acc[n] = fmaf(a, wl[n][kk], acc[n]);
            }
    }
    #pragma unroll
    for (int n = 0; n < 6; n++) part[cig][tid & 31][n] = acc[n];
    __syncthreads();
    if (cig == 0) {
        #pragma unroll
        for (int n = 0; n < 6; n++) {
            float s = 0.f;
            for (int g = 0; g < 8; g++) s += part[g][tid & 31][n];
            c2[(size_t)row * 6 + n] = s;
        }
    }
}

// ====================================================================
// theta / theta_diff / sampling coords (verified rounds 1-6)
// ====================================================================
__global__ __launch_bounds__(TPB)
void theta_aux_k(const float* __restrict__ c2, const int* __restrict__ checkp,
                 float* __restrict__ td, float* __restrict__ gxy)
{
    int n = blockIdx.x * TPB + threadIdx.x;
    if (n >= NT_ALL) return;
    float omc = 1.0f - (float)checkp[0];
    const float I[6] = {1.f, 0.f, 0.f, 0.f, 1.f, 0.f};
    float th[6];
    #pragma unroll
    for (int i = 0; i < 6; i++) {
        float v = c2[(size_t)n * 6 + i] * omc + I[i];
        th[i] = v;
        td[(size_t)n * 6 + i] = I[i] - v;
    }
    int S, loc;
    if (n < N0) { S = S0; loc = n; } else { S = S1; loc = n - N0; }
    int SS = S * S;
    int rem = loc % SS;
    int xx = rem / S, yy = rem % S;
    #pragma unroll
    for (int ky = 0; ky < 3; ky++)
        #pragma unroll
        for (int kx = 0; kx < 3; kx++) {
            float bx = (float)(kx - 1), by = (float)(ky - 1);
            gxy[(size_t)n * 18 + ky * 3 + kx]     = th[0] * bx + th[1] * by + th[2] + 1.0f + (float)xx;
            gxy[(size_t)n * 18 + 9 + ky * 3 + kx] = th[3] * bx + th[4] * by + th[5] + 1.0f + (float)yy;
        }
}

__global__ __launch_bounds__(TPB)
void softstats_k(const float* __restrict__ sc, float* __restrict__ mx, float* __restrict__ sm)
{
    int b = blockIdx.x, tid = threadIdx.x;
    const float* p = sc + (size_t)b * Oo * LT;
    constexpr int PER = Oo * LT;
    __shared__ float red[TPB];
    float m = -3.4e38f;
    for (int i = tid; i < PER; i += TPB) m = fmaxf(m, p[i]);
    red[tid] = m;
    for (int off = 128; off; off >>= 1) { __syncthreads(); if (tid < off) red[tid] = fmaxf(red[tid], red[tid + off]); }
    __syncthreads();
    m = red[0];
    __syncthreads();
    float s = 0.f;
    for (int i = tid; i < PER; i += TPB) s += expf(p[i] - m);
    red[tid] = s;
    for (int off = 128; off; off >>= 1) { __syncthreads(); if (tid < off) red[tid] += red[tid + off]; }
    __syncthreads();
    if (tid == 0) { mx[b] = m; sm[b] = red[0]; }
}

__global__ __launch_bounds__(TPB)
void lik_k(const float* __restrict__ sc, const float* __restrict__ mx,
           const float* __restrict__ sm, float* __restrict__ lik)
{
    int b = blockIdx.x, o = threadIdx.x;
    if (o >= Oo) return;
    const float* p = sc + ((size_t)b * Oo + o) * LT;
    float m = mx[b];
    float s = 0.f;
    for (int i = 0; i < LT; i++) s += expf(p[i] - m);
    lik[b * Oo + o] = s / sm[b];
}

__global__ __launch_bounds__(TPB)
void box_k(const float* __restrict__ sc, const float* __restrict__ lik,
           const float* __restrict__ mx, const float* __restrict__ sm,
           const float* __restrict__ gxy, const int* __restrict__ imdp,
           float* __restrict__ boxes, float* __restrict__ boxesNT,
           float* __restrict__ regpart)
{
    int b = blockIdx.x, tid = threadIdx.x;
    __shared__ float sv[TPB];
    __shared__ int si[TPB];

    float v = (tid < Oo) ? lik[b * Oo + tid] : -3.4e38f;
    sv[tid] = v; si[tid] = tid;
    for (int off = 128; off; off >>= 1) {
        __syncthreads();
        if (tid < off) {
            float v2 = sv[tid + off]; int i2 = si[tid + off];
            if (v2 > sv[tid] || (v2 == sv[tid] && i2 < si[tid])) { sv[tid] = v2; si[tid] = i2; }
        }
    }
    __syncthreads();
    int pred = si[0];
    __syncthreads();

    const float* p = sc + ((size_t)b * Oo + pred) * LT;
    float b5 = -3.4e38f; int i5 = 1 << 30;
    float b4 = -3.4e38f; int i4 = 1 << 30;
    for (int pos = tid; pos < LT; pos += TPB) {
        float s = p[pos];
        if (pos < L5) { if (s > b5) { b5 = s; i5 = pos; } }
        else { int q = pos - L5; if (s > b4) { b4 = s; i4 = q; } }
    }
    sv[tid] = b5; si[tid] = i5;
    for (int off = 128; off; off >>= 1) {
        __syncthreads();
        if (tid < off) {
            float v2 = sv[tid + off]; int i2 = si[tid + off];
            if (v2 > sv[tid] || (v2 == sv[tid] && i2 < si[tid])) { sv[tid] = v2; si[tid] = i2; }
        }
    }
    __syncthreads();
    float m5 = sv[0]; int d5 = si[0];
    __syncthreads();
    sv[tid] = b4; si[tid] = i4;
    for (int off = 128; off; off >>= 1) {
        __syncthreads();
        if (tid < off) {
            float v2 = sv[tid + off]; int i2 = si[tid + off];
            if (v2 > sv[tid] || (v2 == sv[tid] && i2 < si[tid])) { sv[tid] = v2; si[tid] = i2; }
        }
    }
    __syncthreads();
    float m4 = sv[0]; int d4 = si[0];

    if (tid == 0) {
        float m = mx[b], s = sm[b];
        float conf5 = expf(m5 - m) / s;
        float conf4 = expf(m4 - m) / s;
        float imd = (float)imdp[0];
        float lo = 0.f, hi = imd - 1.f;

        int xx5 = d5 % S0, yy5 = d5 / S0;
        int n5 = b * (S0 * S0) + xx5 * S0 + yy5;
        const float* g = gxy + (size_t)n5 * 18;
        float txm = 1e30f, txM = -1e30f, tym = 1e30f, tyM = -1e30f;
        for (int j = 0; j < 9; j++) {
            float tx = g[j] / 9.f, ty = g[9 + j] / 9.f;
            txm = fminf(txm, tx); txM = fmaxf(txM, tx);
            tym = fminf(tym, ty); tyM = fmaxf(tyM, ty);
        }
        float box5[5] = { clampf(txm * imd, lo, hi), clampf(tym * imd, lo, hi),
                          clampf(txM * imd, lo, hi), clampf(tyM * imd, lo, hi), conf5 };
        float nt5[5]  = { clampf((float)xx5 / 9.f * imd, lo, hi), clampf((float)yy5 / 9.f * imd, lo, hi),
                          clampf((float)(xx5 + 2) / 9.f * imd, lo, hi), clampf((float)(yy5 + 2) / 9.f * imd, lo, hi), conf5 };

        int xx4 = d4 % S1, yy4 = d4 / S1;
        int n4 = N0 + b * (S1 * S1) + xx4 * S1 + yy4;
        const float* g4 = gxy + (size_t)n4 * 18;
        float txm4 = 1e30f, txM4 = -1e30f, tym4 = 1e30f, tyM4 = -1e30f;
        for (int j = 0; j < 9; j++) {
            float tx = g4[j] / 19.f, ty = g4[9 + j] / 19.f;
            txm4 = fminf(txm4, tx); txM4 = fmaxf(txM4, tx);
            tym4 = fminf(tym4, ty); tyM4 = fmaxf(tyM4, ty);
        }
        float box4[5] = { clampf(txm4 * imd, lo, hi), clampf(tym4 * imd, lo, hi),
                          clampf(txM4 * imd, lo, hi), clampf(tyM4 * imd, lo, hi), conf4 };
        float nt4[5]  = { clampf((float)xx4 / 19.f * imd, lo, hi), clampf((float)yy4 / 19.f * imd, lo, hi),
                          clampf((float)(xx4 + 2) / 19.f * imd, lo, hi), clampf((float)(yy4 + 2) / 19.f * imd, lo, hi), conf4 };

        int mi = (conf4 > conf5) ? 1 : 0;
        for (int i = 0; i < 5; i++) {
            boxes[b * 5 + i]   = mi ? box4[i] : box5[i];
            boxesNT[b * 5 + i] = mi ? nt4[i] : nt5[i];
        }
        regpart[b] = fmaxf(conf4 - conf5, 0.f);
    }
}

__global__ void reg_k(const float* __restrict__ regpart, float* __restrict__ outreg)
{
    if (threadIdx.x == 0) {
        float s = 0.f;
        for (int b = 0; b < Bb; b++) s += regpart[b];
        outreg[0] = s;
    }
}

__global__ void sentinel_k(float* out, int n)
{
    int i = blockIdx.x * 256 + threadIdx.x;
    if (i < n) out[i] = 12345.0f;
}

extern "C" void kernel_launch(void* const* d_in, const int* in_sizes, int n_in,
                              void* d_out, int out_size, void* d_ws, size_t ws_size,
                              hipStream_t stream)
{
    const float* x0 = (const float*)d_in[0];
    const float* x1 = (const float*)d_in[1];
    const float* w0 = (const float*)d_in[2];
    const float* b0 = (const float*)d_in[3];
    const float* w1 = (const float*)d_in[4];
    const float* cw = (const float*)d_in[5];
    const float* cb = (const float*)d_in[6];
    const float* lw = (const float*)d_in[7];
    const float* lb = (const float*)d_in[8];
    const int* checkp = (const int*)d_in[9];
    const int* imdp   = (const int*)d_in[10];

    if (ws_size < B_END) {
        sentinel_k<<<dim3((out_size + 255) / 256), dim3(256), 0, stream>>>((float*)d_out, out_size);
        return;
    }

    char* wsb = (char*)d_ws;
    short* cwh = (short*)(wsb + B_CWH);
    short* cwl = (short*)(wsb + B_CWL);
    float* gxy = (float*)(wsb + B_GXY);
    short* lwh = (short*)(wsb + B_LWH);
    short* lwl = (short*)(wsb + B_LWL);
    float* sc  = (float*)(wsb + B_SC);
    short* xsH = (short*)(wsb + B_XSH);
    short* xsL = (short*)(wsb + B_XSL);
    short* fcH = (short*)(wsb + B_FCH);
    short* fcL = (short*)(wsb + B_FCL);
    float* mx  = (float*)(wsb + B_MX);
    float* sm  = (float*)(wsb + B_SM);
    float* rp  = (float*)(wsb + B_RP);
    short* w0h = (short*)(wsb + B_W0H);   // alias in xsH region (dead before chunks)
    short* w0l = (short*)(wsb + B_W0L);
    float* h0  = (float*)(wsb + B_H0);    // alias in xsL region (dead before chunks)
    float* h1  = (float*)(wsb + B_H1);
    float* c2  = (float*)(wsb + B_FCH);   // alias in fc region (dead before chunks? c2 read by theta_aux before chunks) 

    float* out   = (float*)d_out;
    float* o_lik = out + O_LIK;
    float* o_box = out + O_BOX;
    float* o_nt  = out + O_NT;
    float* o_td  = out + O_TD;
    float* o_reg = out + O_REG;

    dim3 blk(TPB);

    // weight splits: cw K-perm (j*256+c), w0 tap-16, lw plain
    splitp_k  <<<dim3((int)((SZ_CW  + TPB - 1) / TPB)), blk, 0, stream>>>(cw, cwh, cwl, Ff);
    splitp16_k<<<dim3((int)((SZ_W0P + TPB - 1) / TPB)), blk, 0, stream>>>(w0, w0h, w0l, Cc);
    split_k   <<<dim3((int)((SZ_LW  + TPB - 1) / TPB)), blk, 0, stream>>>(lw, lwh, lwl, (int)SZ_LW);

    // conv1 (+bias, relu) -> h fp32, both scales (round-4 slab path)
    mgemm<0, H0, Cc, KP><<<dim3(2, 25), blk, 0, stream>>>(
        x0, nullptr, nullptr, w0h, w0l, b0, h0, nullptr, nullptr, 0);
    mgemm<0, H1, Cc, KP><<<dim3(2, 100), blk, 0, stream>>>(
        x1, nullptr, nullptr, w0h, w0l, b0, h1, nullptr, nullptr, 0);

    // conv2 (6 ch) -> c2 (aliased in fc region, read immediately by theta_aux)
    conv2_k<<<dim3(NT_ALL / 32), blk, 0, stream>>>(h0, h1, w1, c2);

    // theta, theta_diff, sampling coords
    theta_aux_k<<<dim3((NT_ALL + TPB - 1) / TPB), blk, 0, stream>>>(c2, checkp, o_td, gxy);

    // chunked: materialize xs -> feat GEMM -> scores GEMM (c2 dead now)
    const int nchunk = (NT_ALL + CHUNK - 1) / CHUNK;   // 4
    for (int c = 0; c < nchunk; c++) {
        int basei = c * CHUNK;
        int rows = min(CHUNK, NT_ALL - basei);         // 4096,4096,4096,128
        int mt = rows / 128;
        mat_k<<<dim3((rows * 288 + TPB - 1) / TPB), blk, 0, stream>>>(
            x0, x1, gxy, xsH, xsL, basei, rows);
        mgemm<4, 1, Ff, KC><<<dim3(8, mt), blk, 0, stream>>>(
            nullptr, xsH, xsL, cwh, cwl, cb, nullptr, fcH, fcL, 0);
        mgemm<5, 1, Oo, Ff><<<dim3(2, mt), blk, 0, stream>>>(
            nullptr, fcH, fcL, lwh, lwl, lb, sc, nullptr, nullptr, basei);
    }

    // softmax stats, likelihood, boxes, reg
    softstats_k<<<dim3(Bb), blk, 0, stream>>>(sc, mx, sm);
    lik_k<<<dim3(Bb), blk, 0, stream>>>(sc, mx, sm, o_lik);
    box_k<<<dim3(Bb), blk, 0, stream>>>(sc, o_lik, mx, sm, gxy, imdp, o_box, o_nt, rp);
    reg_k<<<dim3(1), dim3(64), 0, stream>>>(rp, o_reg);
}

// Round 8
// 1219.336 us; speedup vs baseline: 2.4057x; 1.4219x over previous
//
#include <hip/hip_runtime.h>
#include <cmath>

#define TPB 256

// ---- problem constants ----
constexpr int Bb = 32, Cc = 256, Ff = 1024, Oo = 201;
constexpr int H0 = 10, S0 = 8,  N0 = Bb * S0 * S0;   // 2048
constexpr int H1 = 20, S1 = 18, N1 = Bb * S1 * S1;   // 10368
constexpr int NT_ALL = N0 + N1;                      // 12416
constexpr int KC = Cc * 9;                           // 2304
constexpr int KP = Cc * 16;                          // 4096 (tap-padded conv1 K)
constexpr int L5 = S0 * S0, L4 = S1 * S1, LT = L5 + L4;  // 64, 324, 388
constexpr int CHUNK = 4096;
constexpr int M1 = Bb * H0 * H0;                     // 3200 (conv1 scale boundary, tile-aligned)
constexpr int MCONV = M1 + Bb * H1 * H1;             // 16000

// ---- element counts ----
constexpr size_t SZ_CW  = (size_t)Ff * KC;      // 2,359,296
constexpr size_t SZ_W0P = (size_t)Cc * KP;      // 1,048,576
constexpr size_t SZ_LWP = (size_t)256 * Ff;     // 262,144 (padded to 256 rows)

// ---- workspace byte offsets ----
constexpr size_t B_CWH = 0;
constexpr size_t B_CWL = B_CWH + SZ_CW * 2;                 //  4,718,592
constexpr size_t B_GXY = B_CWL + SZ_CW * 2;                 //  9,437,184
constexpr size_t B_LWH = B_GXY + (size_t)NT_ALL * 18 * 4;   // 10,331,136
constexpr size_t B_LWL = B_LWH + SZ_LWP * 2;                // 10,855,424
constexpr size_t B_SC  = B_LWL + SZ_LWP * 2;                // 11,379,712
constexpr size_t B_XSH = B_SC + (size_t)Bb * Oo * LT * 4;   // 21,362,176
constexpr size_t B_XSL = B_XSH + (size_t)CHUNK * KC * 2;    // 40,236,544
constexpr size_t B_FCH = B_XSL + (size_t)CHUNK * KC * 2;    // 59,110,912
constexpr size_t B_FCL = B_FCH + (size_t)CHUNK * Ff * 2;    // 67,499,520
constexpr size_t B_MX  = B_FCL + (size_t)CHUNK * Ff * 2;    // 75,888,128
constexpr size_t B_SM  = B_MX + 128;
constexpr size_t B_RP  = B_SM + 128;
constexpr size_t B_END = B_RP + 128;                        // ~75.9 MB (ws proven >= 78.4 MB)
// aliases (disjoint lifetimes)
constexpr size_t B_W0H = B_XSH;                              // 2 MB
constexpr size_t B_W0L = B_XSH + SZ_W0P * 2;                 // +2 MB (<= 18.9 MB region)
constexpr size_t B_H0  = B_XSL;                              // 3.28 MB
constexpr size_t B_H1  = B_XSL + (size_t)Bb * Cc * H0 * H0 * 4;  // +13.1 MB (<= 18.9)
constexpr size_t B_C2  = B_FCH;                              // 0.30 MB, dead before chunks

// ---- output layout (floats) ----
constexpr size_t O_LIK = 0;
constexpr size_t O_BOX = O_LIK + Bb * Oo;
constexpr size_t O_NT  = O_BOX + Bb * 5;
constexpr size_t O_TD  = O_NT + Bb * 5;
constexpr size_t O_REG = O_TD + (size_t)NT_ALL * 6;

typedef __attribute__((ext_vector_type(8))) short bf16x8;
typedef __attribute__((ext_vector_type(4))) float f32x4;

__device__ __forceinline__ void tsplit(float v, short& h, short& l) {
    unsigned u = __builtin_bit_cast(unsigned, v);
    h = (short)(u >> 16);
    float hf = __builtin_bit_cast(float, u & 0xffff0000u);
    float r = v - hf;                       // exact
    l = (short)(__builtin_bit_cast(unsigned, r) >> 16);
}
__device__ __forceinline__ float clampf(float x, float lo, float hi) {
    return fminf(fmaxf(x, lo), hi);
}
// direct global -> LDS (16 B per lane; dest = base + lane*16)
__device__ __forceinline__ void gload16(const void* g, void* l) {
    __builtin_amdgcn_global_load_lds(
        (const __attribute__((address_space(1))) void*)g,
        (__attribute__((address_space(3))) void*)l, 16, 0, 0);
}

// ===================== weight split kernels =====================
__global__ __launch_bounds__(TPB)
void splitp_k(const float* __restrict__ src, short* __restrict__ hi,
              short* __restrict__ lo, int nrows)   // cw: k' = t*256 + c
{
    int idx = blockIdx.x * TPB + threadIdx.x;
    if (idx >= nrows * KC) return;
    int row = idx / KC, k = idx - row * KC;
    int c = k / 9, t = k - c * 9;
    short h, l; tsplit(src[idx], h, l);
    size_t dst = (size_t)row * KC + t * 256 + c;
    hi[dst] = h; lo[dst] = l;
}

__global__ __launch_bounds__(TPB)
void splitp16_k(const float* __restrict__ src, short* __restrict__ hi,
                short* __restrict__ lo, int nrows) // w0: k' = c*16 + t
{
    int idx = blockIdx.x * TPB + threadIdx.x;
    if (idx >= nrows * KP) return;
    int row = idx >> 12, kq = idx & (KP - 1);
    int c = kq >> 4, t = kq & 15;
    float v = (t < 9) ? src[(size_t)row * KC + c * 9 + t] : 0.f;
    short h, l; tsplit(v, h, l);
    hi[idx] = h; lo[idx] = l;
}

__global__ __launch_bounds__(TPB)
void splitlw_k(const float* __restrict__ src, short* __restrict__ hi,
               short* __restrict__ lo)             // lw, zero-padded to 256 rows
{
    int idx = blockIdx.x * TPB + threadIdx.x;
    if (idx >= (int)SZ_LWP) return;
    int row = idx >> 10;
    float v = (row < Oo) ? src[idx] : 0.f;
    short h, l; tsplit(v, h, l);
    hi[idx] = h; lo[idx] = l;
}

// ===================== mat_k: materialize sampled im2col chunk =====================
__global__ __launch_bounds__(TPB)
void mat_k(const float* __restrict__ x0, const float* __restrict__ x1,
           const float* __restrict__ gxy, short* __restrict__ xsH,
           short* __restrict__ xsL, int base, int rows)
{
    int idx = blockIdx.x * TPB + threadIdx.x;
    if (idx >= rows * 288) return;
    int mloc = idx / 288, r = idx - mloc * 288;
    int j = r >> 5, cg = r & 31;
    int m = base + mloc;
    const float* xp; int H, loc, SS;
    if (m < N0) { xp = x0; H = H0; loc = m; SS = 64; }
    else        { xp = x1; H = H1; loc = m - N0; SS = 324; }
    int b = loc / SS;
    float gx = gxy[(size_t)m * 18 + j];
    float gy = gxy[(size_t)m * 18 + 9 + j];
    float xf = floorf(gx), yf = floorf(gy);
    float wx = gx - xf, wy = gy - yf;
    int ix = (int)xf, iy = (int)yf;
    int cx0 = min(max(ix, 0), H - 1), cy0 = min(max(iy, 0), H - 1);
    bool vx0 = (ix >= 0 && ix < H), vx1 = (ix >= -1 && ix < H - 1);
    bool vy0 = (iy >= 0 && iy < H), vy1 = (iy >= -1 && iy < H - 1);
    float wxL = vx0 ? (1.f - wx) : (vx1 ? wx : 0.f);
    float wxR = (vx0 && vx1) ? wx : 0.f;
    float wyT = vy0 ? (1.f - wy) : (vy1 ? wy : 0.f);
    float wyB = (vy0 && vy1) ? wy : 0.f;
    float wTL = wyT * wxL, wTR = wyT * wxR, wBL = wyB * wxL, wBR = wyB * wxR;
    int o   = cy0 * H + cx0;
    int oTR = (wTR != 0.f) ? o + 1     : o;
    int oBL = (wBL != 0.f) ? o + H     : o;
    int oBR = (wBR != 0.f) ? o + H + 1 : o;
    const float* cp = xp + ((size_t)b * Cc + cg * 8) * (H * H);
    bf16x8 hv, lv;
    #pragma unroll
    for (int e = 0; e < 8; e++) {
        float v = cp[o] * wTL + cp[oTR] * wTR + cp[oBL] * wBL + cp[oBR] * wBR;
        short h, l; tsplit(v, h, l); hv[e] = h; lv[e] = l;
        cp += H * H;
    }
    size_t dst = (size_t)mloc * KC + j * 256 + cg * 8;
    *(bf16x8*)&xsH[dst] = hv;
    *(bf16x8*)&xsL[dst] = lv;
}

// =====================================================================
// Split-bf16 MFMA GEMM. Block tile 128x64, 4 waves (2M x 2N, 64x32 each),
// BK=32, mfma_f32_16x16x32_bf16, 3 MFMAs per hi/lo pair.
// MODE 0: merged conv1 (both scales; runtime H per m-tile). A = im2col
//         pad=1 via LDS slab (K tap-padded, KD=KP); B via global_load_lds.
//         epilogue relu fp32 -> h0/h1.
// MODE 4: A,B presplit, both staged via global_load_lds (KD=KC);
//         epilogue feat hi/lo bf16.
// MODE 5: A,B presplit via global_load_lds (KD=Ff, B zero-padded to 256
//         rows); epilogue score scatter, runtime scale split (base+gm).
// GRID: dim3(nN, nM) -- n fastest (XCD B-strip pinning).
// =====================================================================
template<int MODE, int KD>
__global__ __launch_bounds__(TPB, 2)
void mgemm(const float* __restrict__ x0s, const float* __restrict__ x1s,
           const short* __restrict__ AsH, const short* __restrict__ AsL,
           const short* __restrict__ Bh, const short* __restrict__ Bl,
           const float* __restrict__ bias,
           float* __restrict__ outF, float* __restrict__ outF2,
           short* __restrict__ outH, short* __restrict__ outL, int base)
{
    __shared__ short As[2][4][128][8];   // 16 KB
    __shared__ short Bs[2][4][64][8];    //  8 KB
    __shared__ float slab[(MODE == 0) ? 1600 : 1];

    const int tid = threadIdx.x;
    const int lane = tid & 63;
    const int wid = tid >> 6;
    const int wm = (wid >> 1) * 64, wn = (wid & 1) * 32;
    const int ml = tid & 127, kg0 = tid >> 7;
    const int bm = blockIdx.y * 128, bn = blockIdx.x * 64;   // n fastest

    f32x4 acc[4][2];
    #pragma unroll
    for (int i = 0; i < 4; i++)
        #pragma unroll
        for (int j = 0; j < 2; j++)
            acc[i][j] = (f32x4){0.f, 0.f, 0.f, 0.f};

    // ---- MODE 0: runtime scale + tap tables + slab geometry ----
    const float* xsrc = nullptr;
    int Hh = 0, PLSZr = 0, UPPr = 0, bat0 = 0, batidx = 0, nu = 0;
    float wvt[9]; int offt[9];
    if constexpr (MODE == 0) {
        int lbase;
        if (bm < M1) { xsrc = x0s; Hh = H0; lbase = bm; }
        else         { xsrc = x1s; Hh = H1; lbase = bm - M1; }
        PLSZr = Hh * Hh; UPPr = PLSZr >> 2;
        int mGl = lbase + ml;
        int bA = mGl / PLSZr; int rem = mGl - bA * PLSZr;
        int yA = rem / Hh, xA = rem - (rem / Hh) * Hh;
        bat0 = lbase / PLSZr;
        int nb = (lbase + 127) / PLSZr - bat0 + 1;
        batidx = bA - bat0;
        nu = nb * 2 * UPPr;
        #pragma unroll
        for (int t = 0; t < 9; t++) {
            int ky = t / 3 - 1, kx = t - (t / 3) * 3 - 1;
            int yy = yA + ky, xx = xA + kx;
            bool ok = (yy >= 0 && yy < Hh && xx >= 0 && xx < Hh);
            offt[t] = ok ? (yy * Hh + xx) : 0;
            wvt[t] = ok ? 1.f : 0.f;
        }
    }

    for (int kb = 0; kb < KD; kb += 32) {
        if constexpr (MODE == 0) {
            // ---- phase 0: slab stage (channels c0, c0+1) ----
            const int c0 = kb >> 4;
            for (int i = tid; i < nu; i += TPB) {
                int pl = i / UPPr, u = i - pl * UPPr;
                int bi = pl >> 1, cc = pl & 1;
                *(float4*)&slab[pl * PLSZr + u * 4] =
                    *(const float4*)(xsrc + ((size_t)(bat0 + bi) * Cc + c0 + cc) * PLSZr + u * 4);
            }
            __syncthreads();
            // ---- B direct-to-LDS ----
            #pragma unroll
            for (int s8 = 0; s8 < 2; s8++) {
                int s = wid + s8 * 4;
                int hilo = s & 1, kg = s >> 1;
                const short* g = (hilo ? Bl : Bh) + (size_t)(bn + lane) * KD + kb + kg * 8;
                gload16(g, &Bs[hilo][kg][0][0]);
            }
            // ---- A gather from slab ----
            const float* sp = &slab[(batidx * 2 + kg0) * PLSZr];
            bf16x8 hv, lv;
            #pragma unroll
            for (int e = 0; e < 8; e++) {
                float v = sp[offt[e]] * wvt[e];
                short h, l; tsplit(v, h, l); hv[e] = h; lv[e] = l;
            }
            *(bf16x8*)&As[0][kg0 * 2][ml][0] = hv;
            *(bf16x8*)&As[1][kg0 * 2][ml][0] = lv;
            bf16x8 hv2 = {}, lv2 = {};
            { float v = sp[offt[8]] * wvt[8];
              short h, l; tsplit(v, h, l); hv2[0] = h; lv2[0] = l; }
            *(bf16x8*)&As[0][kg0 * 2 + 1][ml][0] = hv2;
            *(bf16x8*)&As[1][kg0 * 2 + 1][ml][0] = lv2;
            __syncthreads();
        } else {
            // ---- A + B direct-to-LDS (wave-distributed slabs) ----
            #pragma unroll
            for (int s8 = 0; s8 < 4; s8++) {
                int s = wid + s8 * 4;
                int hilo = s & 1, kg = (s >> 1) & 3, half = s >> 3;
                const short* g = (hilo ? AsL : AsH) + (size_t)(bm + half * 64 + lane) * KD + kb + kg * 8;
                gload16(g, &As[hilo][kg][half * 64][0]);
            }
            #pragma unroll
            for (int s8 = 0; s8 < 2; s8++) {
                int s = wid + s8 * 4;
                int hilo = s & 1, kg = s >> 1;
                const short* g = (hilo ? Bl : Bh) + (size_t)(bn + lane) * KD + kb + kg * 8;
                gload16(g, &Bs[hilo][kg][0][0]);
            }
            __syncthreads();
        }
        // ---- MFMA ----
        {
            const int kq = lane >> 4, r = lane & 15;
            bf16x8 ah[4], al[4], bhf[2], blf[2];
            #pragma unroll
            for (int i = 0; i < 4; i++) {
                ah[i] = *(const bf16x8*)&As[0][kq][wm + i * 16 + r][0];
                al[i] = *(const bf16x8*)&As[1][kq][wm + i * 16 + r][0];
            }
            #pragma unroll
            for (int j = 0; j < 2; j++) {
                bhf[j] = *(const bf16x8*)&Bs[0][kq][wn + j * 16 + r][0];
                blf[j] = *(const bf16x8*)&Bs[1][kq][wn + j * 16 + r][0];
            }
            #pragma unroll
            for (int i = 0; i < 4; i++)
                #pragma unroll
                for (int j = 0; j < 2; j++) {
                    acc[i][j] = __builtin_amdgcn_mfma_f32_16x16x32_bf16(ah[i], bhf[j], acc[i][j], 0, 0, 0);
                    acc[i][j] = __builtin_amdgcn_mfma_f32_16x16x32_bf16(al[i], bhf[j], acc[i][j], 0, 0, 0);
                    acc[i][j] = __builtin_amdgcn_mfma_f32_16x16x32_bf16(ah[i], blf[j], acc[i][j], 0, 0, 0);
                }
        }
        __syncthreads();
    }

    // ---------- epilogue ----------
    const int kq = lane >> 4, rr = lane & 15;
    #pragma unroll
    for (int i = 0; i < 4; i++) {
        #pragma unroll
        for (int r = 0; r < 4; r++) {
            const int gm = bm + wm + i * 16 + kq * 4 + r;
            #pragma unroll
            for (int j = 0; j < 2; j++) {
                const int gn = bn + wn + j * 16 + rr;
                float v = acc[i][j][r];
                if constexpr (MODE == 0) {
                    float* hp; int Hq, lr;
                    if (gm < M1) { hp = outF; Hq = H0; lr = gm; }
                    else         { hp = outF2; Hq = H1; lr = gm - M1; }
                    int PL = Hq * Hq;
                    int bq = lr / PL; int rem = lr - bq * PL;
                    int yq = rem / Hq; int xq = rem - yq * Hq;
                    hp[((size_t)bq * Cc + gn) * PL + yq * Hq + xq] = fmaxf(v + bias[gn], 0.f);
                } else if constexpr (MODE == 4) {
                    float q = fmaxf(v + bias[gn], 0.f);
                    short h, l; tsplit(q, h, l);
                    outH[(size_t)gm * Ff + gn] = h;
                    outL[(size_t)gm * Ff + gn] = l;
                } else { // MODE 5
                    if (gn < Oo) {
                        int g = base + gm;
                        int bq, pos;
                        if (g < N0) {
                            int lo = g & 63; bq = g >> 6;
                            pos = (lo & 7) * 8 + (lo >> 3);
                        } else {
                            int gg = g - N0; bq = gg / 324; int lo = gg - bq * 324;
                            int xq = lo / 18, yq = lo - xq * 18;
                            pos = L5 + yq * 18 + xq;
                        }
                        outF[((size_t)bq * Oo + gn) * LT + pos] = v + bias[gn];
                    }
                }
            }
        }
    }
}

// ===================== conv2 =====================
__global__ __launch_bounds__(TPB)
void conv2_k(const float* __restrict__ h0, const float* __restrict__ h1,
             const float* __restrict__ w1, float* __restrict__ c2)
{
    __shared__ float wl[6][KC];
    __shared__ float part[8][32][6];
    const int tid = threadIdx.x;
    for (int i = tid; i < 6 * KC; i += TPB) wl[i / KC][i - (i / KC) * KC] = w1[i];
    __syncthreads();
    const int row = blockIdx.x * 32 + (tid & 31);
    const int cig = tid >> 5;
    const float* hsrc; int H, S, loc;
    if (row < N0) { hsrc = h0; H = H0; S = S0; loc = row; }
    else          { hsrc = h1; H = H1; S = S1; loc = row - N0; }
    int SS = S * S;
    int b = loc / SS; int rem = loc - b * SS;
    int xq = rem / S; int yq = rem - xq * S;
    float acc[6] = {};
    for (int ci = cig * 32; ci < cig * 32 + 32; ci++) {
        const float* hp = hsrc + ((size_t)(b * Cc + ci) * H + yq) * H + xq;
        #pragma unroll
        for (int ky = 0; ky < 3; ky++)
            #pragma unroll
            for (int kx = 0; kx < 3; kx++) {
                float a = hp[ky * H + kx];
                int kk = ci * 9 + ky * 3 + kx;
                #pragma unroll
                for (int n = 0; n < 6; n++) acc[n] = fmaf(a, wl[n][kk], acc[n]);
            }
    }
    #pragma unroll
    for (int n = 0; n < 6; n++) part[cig][tid & 31][n] = acc[n];
    __syncthreads();
    if (cig == 0) {
        #pragma unroll
        for (int n = 0; n < 6; n++) {
            float s = 0.f;
            for (int g = 0; g < 8; g++) s += part[g][tid & 31][n];
            c2[(size_t)row * 6 + n] = s;
        }
    }
}

// ===================== theta / aux =====================
__global__ __launch_bounds__(TPB)
void theta_aux_k(const float* __restrict__ c2, const int* __restrict__ checkp,
                 float* __restrict__ td, float* __restrict__ gxy)
{
    int n = blockIdx.x * TPB + threadIdx.x;
    if (n >= NT_ALL) return;
    float omc = 1.0f - (float)checkp[0];
    const float I[6] = {1.f, 0.f, 0.f, 0.f, 1.f, 0.f};
    float th[6];
    #pragma unroll
    for (int i = 0; i < 6; i++) {
        float v = c2[(size_t)n * 6 + i] * omc + I[i];
        th[i] = v;
        td[(size_t)n * 6 + i] = I[i] - v;
    }
    int S, loc;
    if (n < N0) { S = S0; loc = n; } else { S = S1; loc = n - N0; }
    int SS = S * S;
    int rem = loc % SS;
    int xx = rem / S, yy = rem % S;
    #pragma unroll
    for (int ky = 0; ky < 3; ky++)
        #pragma unroll
        for (int kx = 0; kx < 3; kx++) {
            float bx = (float)(kx - 1), by = (float)(ky - 1);
            gxy[(size_t)n * 18 + ky * 3 + kx]     = th[0] * bx + th[1] * by + th[2] + 1.0f + (float)xx;
            gxy[(size_t)n * 18 + 9 + ky * 3 + kx] = th[3] * bx + th[4] * by + th[5] + 1.0f + (float)yy;
        }
}

__global__ __launch_bounds__(TPB)
void softstats_k(const float* __restrict__ sc, float* __restrict__ mx, float* __restrict__ sm)
{
    int b = blockIdx.x, tid = threadIdx.x;
    const float* p = sc + (size_t)b * Oo * LT;
    constexpr int PER = Oo * LT;
    __shared__ float red[TPB];
    float m = -3.4e38f;
    for (int i = tid; i < PER; i += TPB) m = fmaxf(m, p[i]);
    red[tid] = m;
    for (int off = 128; off; off >>= 1) { __syncthreads(); if (tid < off) red[tid] = fmaxf(red[tid], red[tid + off]); }
    __syncthreads();
    m = red[0];
    __syncthreads();
    float s = 0.f;
    for (int i = tid; i < PER; i += TPB) s += expf(p[i] - m);
    red[tid] = s;
    for (int off = 128; off; off >>= 1) { __syncthreads(); if (tid < off) red[tid] += red[tid + off]; }
    __syncthreads();
    if (tid == 0) { mx[b] = m; sm[b] = red[0]; }
}

__global__ __launch_bounds__(TPB)
void lik_k(const float* __restrict__ sc, const float* __restrict__ mx,
           const float* __restrict__ sm, float* __restrict__ lik)
{
    int b = blockIdx.x, o = threadIdx.x;
    if (o >= Oo) return;
    const float* p = sc + ((size_t)b * Oo + o) * LT;
    float m = mx[b];
    float s = 0.f;
    for (int i = 0; i < LT; i++) s += expf(p[i] - m);
    lik[b * Oo + o] = s / sm[b];
}

__global__ __launch_bounds__(TPB)
void box_k(const float* __restrict__ sc, const float* __restrict__ lik,
           const float* __restrict__ mx, const float* __restrict__ sm,
           const float* __restrict__ gxy, const int* __restrict__ imdp,
           float* __restrict__ boxes, float* __restrict__ boxesNT,
           float* __restrict__ regpart)
{
    int b = blockIdx.x, tid = threadIdx.x;
    __shared__ float sv[TPB];
    __shared__ int si[TPB];

    float v = (tid < Oo) ? lik[b * Oo + tid] : -3.4e38f;
    sv[tid] = v; si[tid] = tid;
    for (int off = 128; off; off >>= 1) {
        __syncthreads();
        if (tid < off) {
            float v2 = sv[tid + off]; int i2 = si[tid + off];
            if (v2 > sv[tid] || (v2 == sv[tid] && i2 < si[tid])) { sv[tid] = v2; si[tid] = i2; }
        }
    }
    __syncthreads();
    int pred = si[0];
    __syncthreads();

    const float* p = sc + ((size_t)b * Oo + pred) * LT;
    float b5 = -3.4e38f; int i5 = 1 << 30;
    float b4 = -3.4e38f; int i4 = 1 << 30;
    for (int pos = tid; pos < LT; pos += TPB) {
        float s = p[pos];
        if (pos < L5) { if (s > b5) { b5 = s; i5 = pos; } }
        else { int q = pos - L5; if (s > b4) { b4 = s; i4 = q; } }
    }
    sv[tid] = b5; si[tid] = i5;
    for (int off = 128; off; off >>= 1) {
        __syncthreads();
        if (tid < off) {
            float v2 = sv[tid + off]; int i2 = si[tid + off];
            if (v2 > sv[tid] || (v2 == sv[tid] && i2 < si[tid])) { sv[tid] = v2; si[tid] = i2; }
        }
    }
    __syncthreads();
    float m5 = sv[0]; int d5 = si[0];
    __syncthreads();
    sv[tid] = b4; si[tid] = i4;
    for (int off = 128; off; off >>= 1) {
        __syncthreads();
        if (tid < off) {
            float v2 = sv[tid + off]; int i2 = si[tid + off];
            if (v2 > sv[tid] || (v2 == sv[tid] && i2 < si[tid])) { sv[tid] = v2; si[tid] = i2; }
        }
    }
    __syncthreads();
    float m4 = sv[0]; int d4 = si[0];

    if (tid == 0) {
        float m = mx[b], s = sm[b];
        float conf5 = expf(m5 - m) / s;
        float conf4 = expf(m4 - m) / s;
        float imd = (float)imdp[0];
        float lo = 0.f, hi = imd - 1.f;

        int xx5 = d5 % S0, yy5 = d5 / S0;
        int n5 = b * (S0 * S0) + xx5 * S0 + yy5;
        const float* g = gxy + (size_t)n5 * 18;
        float txm = 1e30f, txM = -1e30f, tym = 1e30f, tyM = -1e30f;
        for (int j = 0; j < 9; j++) {
            float tx = g[j] / 9.f, ty = g[9 + j] / 9.f;
            txm = fminf(txm, tx); txM = fmaxf(txM, tx);
            tym = fminf(tym, ty); tyM = fmaxf(tyM, ty);
        }
        float box5[5] = { clampf(txm * imd, lo, hi), clampf(tym * imd, lo, hi),
                          clampf(txM * imd, lo, hi), clampf(tyM * imd, lo, hi), conf5 };
        float nt5[5]  = { clampf((float)xx5 / 9.f * imd, lo, hi), clampf((float)yy5 / 9.f * imd, lo, hi),
                          clampf((float)(xx5 + 2) / 9.f * imd, lo, hi), clampf((float)(yy5 + 2) / 9.f * imd, lo, hi), conf5 };

        int xx4 = d4 % S1, yy4 = d4 / S1;
        int n4 = N0 + b * (S1 * S1) + xx4 * S1 + yy4;
        const float* g4 = gxy + (size_t)n4 * 18;
        float txm4 = 1e30f, txM4 = -1e30f, tym4 = 1e30f, tyM4 = -1e30f;
        for (int j = 0; j < 9; j++) {
            float tx = g4[j] / 19.f, ty = g4[9 + j] / 19.f;
            txm4 = fminf(txm4, tx); txM4 = fmaxf(txM4, tx);
            tym4 = fminf(tym4, ty); tyM4 = fmaxf(tyM4, ty);
        }
        float box4[5] = { clampf(txm4 * imd, lo, hi), clampf(tym4 * imd, lo, hi),
                          clampf(txM4 * imd, lo, hi), clampf(tyM4 * imd, lo, hi), conf4 };
        float nt4[5]  = { clampf((float)xx4 / 19.f * imd, lo, hi), clampf((float)yy4 / 19.f * imd, lo, hi),
                          clampf((float)(xx4 + 2) / 19.f * imd, lo, hi), clampf((float)(yy4 + 2) / 19.f * imd, lo, hi), conf4 };

        int mi = (conf4 > conf5) ? 1 : 0;
        for (int i = 0; i < 5; i++) {
            boxes[b * 5 + i]   = mi ? box4[i] : box5[i];
            boxesNT[b * 5 + i] = mi ? nt4[i] : nt5[i];
        }
        regpart[b] = fmaxf(conf4 - conf5, 0.f);
    }
}

__global__ void reg_k(const float* __restrict__ regpart, float* __restrict__ outreg)
{
    if (threadIdx.x == 0) {
        float s = 0.f;
        for (int b = 0; b < Bb; b++) s += regpart[b];
        outreg[0] = s;
    }
}

__global__ void sentinel_k(float* out, int n)
{
    int i = blockIdx.x * 256 + threadIdx.x;
    if (i < n) out[i] = 12345.0f;
}

extern "C" void kernel_launch(void* const* d_in, const int* in_sizes, int n_in,
                              void* d_out, int out_size, void* d_ws, size_t ws_size,
                              hipStream_t stream)
{
    const float* x0 = (const float*)d_in[0];
    const float* x1 = (const float*)d_in[1];
    const float* w0 = (const float*)d_in[2];
    const float* b0 = (const float*)d_in[3];
    const float* w1 = (const float*)d_in[4];
    const float* cw = (const float*)d_in[5];
    const float* cb = (const float*)d_in[6];
    const float* lw = (const float*)d_in[7];
    const float* lb = (const float*)d_in[8];
    const int* checkp = (const int*)d_in[9];
    const int* imdp   = (const int*)d_in[10];

    if (ws_size < B_END) {
        sentinel_k<<<dim3((out_size + 255) / 256), dim3(256), 0, stream>>>((float*)d_out, out_size);
        return;
    }

    char* wsb = (char*)d_ws;
    short* cwh = (short*)(wsb + B_CWH);
    short* cwl = (short*)(wsb + B_CWL);
    float* gxy = (float*)(wsb + B_GXY);
    short* lwh = (short*)(wsb + B_LWH);
    short* lwl = (short*)(wsb + B_LWL);
    float* sc  = (float*)(wsb + B_SC);
    short* xsH = (short*)(wsb + B_XSH);
    short* xsL = (short*)(wsb + B_XSL);
    short* fcH = (short*)(wsb + B_FCH);
    short* fcL = (short*)(wsb + B_FCL);
    float* mx  = (float*)(wsb + B_MX);
    float* sm  = (float*)(wsb + B_SM);
    float* rp  = (float*)(wsb + B_RP);
    short* w0h = (short*)(wsb + B_W0H);   // aliases, dead before chunks
    short* w0l = (short*)(wsb + B_W0L);
    float* h0  = (float*)(wsb + B_H0);
    float* h1  = (float*)(wsb + B_H1);
    float* c2  = (float*)(wsb + B_C2);

    float* out   = (float*)d_out;
    float* o_lik = out + O_LIK;
    float* o_box = out + O_BOX;
    float* o_nt  = out + O_NT;
    float* o_td  = out + O_TD;
    float* o_reg = out + O_REG;

    dim3 blk(TPB);

    // weight splits
    splitp_k  <<<dim3((int)((SZ_CW  * 1 + TPB - 1) / TPB)), blk, 0, stream>>>(cw, cwh, cwl, Ff);
    splitp16_k<<<dim3((int)((SZ_W0P + TPB - 1) / TPB)), blk, 0, stream>>>(w0, w0h, w0l, Cc);
    splitlw_k <<<dim3((int)((SZ_LWP + TPB - 1) / TPB)), blk, 0, stream>>>(lw, lwh, lwl);

    // merged conv1 (+bias, relu) -> h0/h1   [grid (4, 125)]
    mgemm<0, KP><<<dim3(4, MCONV / 128), blk, 0, stream>>>(
        x0, x1, nullptr, nullptr, w0h, w0l, b0, h0, h1, nullptr, nullptr, 0);

    // conv2 -> c2
    conv2_k<<<dim3(NT_ALL / 32), blk, 0, stream>>>(h0, h1, w1, c2);

    // theta, theta_diff, sampling coords
    theta_aux_k<<<dim3((NT_ALL + TPB - 1) / TPB), blk, 0, stream>>>(c2, checkp, o_td, gxy);

    // chunked: materialize xs -> feat GEMM -> scores GEMM
    const int nchunk = (NT_ALL + CHUNK - 1) / CHUNK;   // 4
    for (int c = 0; c < nchunk; c++) {
        int basei = c * CHUNK;
        int rows = min(CHUNK, NT_ALL - basei);         // 4096,4096,4096,128
        int mt = rows / 128;
        mat_k<<<dim3((rows * 288 + TPB - 1) / TPB), blk, 0, stream>>>(
            x0, x1, gxy, xsH, xsL, basei, rows);
        mgemm<4, KC><<<dim3(16, mt), blk, 0, stream>>>(
            nullptr, nullptr, xsH, xsL, cwh, cwl, cb, nullptr, nullptr, fcH, fcL, 0);
        mgemm<5, Ff><<<dim3(4, mt), blk, 0, stream>>>(
            nullptr, nullptr, fcH, fcL, lwh, lwl, lb, sc, nullptr, nullptr, nullptr, basei);
    }

    // softmax stats, likelihood, boxes, reg
    softstats_k<<<dim3(Bb), blk, 0, stream>>>(sc, mx, sm);
    lik_k<<<dim3(Bb), blk, 0, stream>>>(sc, mx, sm, o_lik);
    box_k<<<dim3(Bb), blk, 0, stream>>>(sc, o_lik, mx, sm, gxy, imdp, o_box, o_nt, rp);
    reg_k<<<dim3(1), dim3(64), 0, stream>>>(rp, o_reg);
}